// Round 9
// baseline (735.443 us; speedup 1.0000x reference)
//
#include <hip/hip_runtime.h>
#include <hip/hip_bf16.h>

// Decoder forward: embed+posenc -> causal self-attn -> LN -> cross-attn(img) -> LN -> vocab proj
// B=8 S=512 D=1024 DI=768 NI=197(pad 224) V=32000. GEMMs bf16 MFMA (16x16x32), f32 accum.
// R9: vocab GEMM -> ring-2 (64KB LDS) 2-blocks/CU, UNCAPPED registers (R5 retried without
//     the launch_bounds(512,4) reg cap that caused the spill). Inter-block overlap fills
//     the per-tile vmcnt(0)/barrier stalls. Everything else identical to R8.

#define DEV __device__ __forceinline__

typedef __bf16 bf16x8 __attribute__((ext_vector_type(8)));
typedef float f32x4 __attribute__((ext_vector_type(4)));
typedef unsigned int u32;
typedef __hip_bfloat16 bf16;

DEV void llds16(const void* g, void* l) {
  __builtin_amdgcn_global_load_lds((const __attribute__((address_space(1))) u32*)g,
                                   (__attribute__((address_space(3))) u32*)l, 16, 0, 0);
}

DEV float wredsum(float v){
#pragma unroll
  for (int o = 32; o; o >>= 1) v += __shfl_xor(v, o, 64);
  return v;
}
DEV float wredmax(float v){
#pragma unroll
  for (int o = 32; o; o >>= 1) v = fmaxf(v, __shfl_xor(v, o, 64));
  return v;
}

DEV void store_out(float* p, float v){ *p = v; }
DEV void store_out(bf16* p, float v){ *p = __float2bfloat16(v); }

// ================= big GEMM: C[M,N] = A[M,K] @ Bt[N,K]^T + bias =================
// 256x256 tile, BK=32, 8 waves (2Mx4N), per-wave 128x64 = 8x4 frags of 16x16x32.
// LDS: 2-slot ring x (A 16KB + B 16KB) = 64 KiB -> 2 blocks/CU (LDS-limited, regs uncapped).
// Per tile: stage t+1 (slot (t+1)&1, disjoint from read slot t&1); read frags; MFMA;
// vmcnt(0) (loads had the whole iteration in flight); ONE barrier.
// T2 swizzle (pre-swizzled global source + swizzled ds_read): 0 bank conflicts.
// T1 XCD-bijective block swizzle; T5 setprio. Requires: M%256==0, N%256==0, K%32==0, K>=64.
template<typename OutT>
__global__ __launch_bounds__(512) void gemm256_kernel(
    const bf16* __restrict__ A, const bf16* __restrict__ Bt, OutT* __restrict__ C,
    const float* __restrict__ bias, int M, int N, int K, int lda, int ldb, int ldc)
{
  __shared__ alignas(16) char lds[65536];
  const int tid  = threadIdx.x;
  const int wave = tid >> 6, lane = tid & 63;
  const int lo = lane & 15, hi = lane >> 4;
  const int hi2 = hi ^ ((lo >> 1) & 3);            // swizzled 16B slot for ds_read
  const int wr = wave >> 2, wc = wave & 3;
  const int koff = (((lane & 3) ^ ((lane >> 3) & 3)) << 3);  // pre-swizzled global k (write side)

  const int nbx = M >> 8;
  const int nwg = nbx * (N >> 8);
  int id = blockIdx.x;
  int g = (nwg & 7) ? id : ((id & 7) * (nwg >> 3) + (id >> 3));
  const int row0 = (g % nbx) * 256, col0 = (g / nbx) * 256;
  const int NT = K >> 5;
  const int srow = lane >> 2;

  auto stageA = [&](int t) {
    char* base = lds + (t & 1) * 32768;
    const int kk = (t << 5) + koff;
#pragma unroll
    for (int j = 0; j < 2; j++) {
      const int seg = j * 8 + wave;
      llds16(A + (long)(row0 + seg * 16 + srow) * lda + kk, base + seg * 1024);
    }
  };
  auto stageB = [&](int t) {
    char* base = lds + (t & 1) * 32768 + 16384;
    const int kk = (t << 5) + koff;
#pragma unroll
    for (int j = 0; j < 2; j++) {
      const int seg = j * 8 + wave;
      llds16(Bt + (long)(col0 + seg * 16 + srow) * ldb + kk, base + seg * 1024);
    }
  };

  f32x4 acc[8][4] = {};

  // prologue: stage tile 0, drain, sync.
  stageA(0); stageB(0);
  asm volatile("s_waitcnt vmcnt(0)" ::: "memory");
  __builtin_amdgcn_s_barrier();
  __builtin_amdgcn_sched_barrier(0);

  for (int t = 0; t < NT; t++) {
    const char* As = lds + (t & 1) * 32768;
    const char* Bs = As + 16384;
    // issue next tile's staging first: lands during this tile's reads + MFMA
    if (t + 1 < NT) { stageA(t + 1); stageB(t + 1); }
    bf16x8 af[4], bfv[4];
#pragma unroll
    for (int n = 0; n < 4; n++)
      bfv[n] = *(const bf16x8*)(Bs + ((wc * 64 + n * 16 + lo) << 6) + (hi2 << 4));
#pragma unroll
    for (int m = 0; m < 4; m++)
      af[m] = *(const bf16x8*)(As + ((wr * 128 + m * 16 + lo) << 6) + (hi2 << 4));
    __builtin_amdgcn_s_setprio(1);
#pragma unroll
    for (int m = 0; m < 4; m++)
#pragma unroll
      for (int n = 0; n < 4; n++)
        acc[m][n] = __builtin_amdgcn_mfma_f32_16x16x32_bf16(af[m], bfv[n], acc[m][n], 0, 0, 0);
    __builtin_amdgcn_s_setprio(0);
#pragma unroll
    for (int m = 0; m < 4; m++)
      af[m] = *(const bf16x8*)(As + ((wr * 128 + (m + 4) * 16 + lo) << 6) + (hi2 << 4));
    __builtin_amdgcn_s_setprio(1);
#pragma unroll
    for (int m = 0; m < 4; m++)
#pragma unroll
      for (int n = 0; n < 4; n++)
        acc[m + 4][n] = __builtin_amdgcn_mfma_f32_16x16x32_bf16(af[m], bfv[n], acc[m + 4][n], 0, 0, 0);
    __builtin_amdgcn_s_setprio(0);
    __builtin_amdgcn_sched_barrier(0);
    asm volatile("s_waitcnt vmcnt(0)" ::: "memory");
    __builtin_amdgcn_sched_barrier(0);
    __builtin_amdgcn_s_barrier();
    __builtin_amdgcn_sched_barrier(0);
  }

#pragma unroll
  for (int m = 0; m < 8; m++) {
    const int r = row0 + wr * 128 + m * 16 + hi * 4;
#pragma unroll
    for (int n = 0; n < 4; n++) {
      const int c = col0 + wc * 64 + n * 16 + lo;
      const float bb = bias ? bias[c] : 0.0f;
#pragma unroll
      for (int j = 0; j < 4; j++)
        store_out(&C[(long)(r + j) * ldc + c], acc[m][n][j] + bb);
    }
  }
}

// ---------------- GEMM: C[M,N] = A[M,K] @ Bt[N,K]^T (+bias[N]) ----------------
// 128x128 tile, BK=32, 4 waves (2x2), T2-swizzled, bounds-guarded (general shapes).
template<typename OutT>
__global__ __launch_bounds__(256) void gemm_bt_kernel(
    const bf16* __restrict__ A, const bf16* __restrict__ Bt, OutT* __restrict__ C,
    const float* __restrict__ bias, int M, int N, int K,
    int lda, int ldb, int ldc, long sA, long sB, long sC)
{
  A  += (long)blockIdx.z * sA;
  Bt += (long)blockIdx.z * sB;
  C  += (long)blockIdx.z * sC;
  __shared__ alignas(16) bf16 As[128*32];
  __shared__ alignas(16) bf16 Bs[128*32];
  const int tid = threadIdx.x;
  const int wave = tid >> 6, lane = tid & 63;
  const int lo = lane & 15, hi = lane >> 4;
  const int hi2 = hi ^ ((lo >> 1) & 3);
  const int wr = wave >> 1, wc = wave & 1;
  const int row0 = blockIdx.x * 128, col0 = blockIdx.y * 128;
  const int srow  = lane >> 2;
  const int skoff = (((lane & 3) ^ ((lane >> 3) & 3)) << 3);

  f32x4 acc[4][4] = {};

  for (int k0 = 0; k0 < K; k0 += 32) {
#pragma unroll
    for (int c = 0; c < 2; ++c) {
      const int seg = c*4 + wave;
      int ra = row0 + seg*16 + srow; ra = ra < M ? ra : M-1;
      llds16(A + (long)ra*lda + (k0 + skoff), (char*)As + seg*1024);
      int rb = col0 + seg*16 + srow; rb = rb < N ? rb : N-1;
      llds16(Bt + (long)rb*ldb + (k0 + skoff), (char*)Bs + seg*1024);
    }
    __syncthreads();
    bf16x8 af[4], bfv[4];
#pragma unroll
    for (int m = 0; m < 4; m++)
      af[m] = *(const bf16x8*)((const char*)As + (wr*64 + m*16 + lo)*64 + hi2*16);
#pragma unroll
    for (int n = 0; n < 4; n++)
      bfv[n] = *(const bf16x8*)((const char*)Bs + (wc*64 + n*16 + lo)*64 + hi2*16);
#pragma unroll
    for (int m = 0; m < 4; m++)
#pragma unroll
      for (int n = 0; n < 4; n++)
        acc[m][n] = __builtin_amdgcn_mfma_f32_16x16x32_bf16(af[m], bfv[n], acc[m][n], 0, 0, 0);
    __syncthreads();
  }

#pragma unroll
  for (int m = 0; m < 4; m++) {
    const int rbase = row0 + wr*64 + m*16 + hi*4;
#pragma unroll
    for (int n = 0; n < 4; n++) {
      const int cc = col0 + wc*64 + n*16 + lo;
      if (cc >= N) continue;
      const float bb = bias ? bias[cc] : 0.0f;
#pragma unroll
      for (int j = 0; j < 4; j++) {
        const int rr = rbase + j;
        if (rr < M) store_out(&C[(long)rr*ldc + cc], acc[m][n][j] + bb);
      }
    }
  }
}

// ---------------- weight prep: W[K,N] f32 -> Wt[N,K] bf16, z-indexed up to 4 pairs ----------------
__global__ __launch_bounds__(256) void wprep4_kernel(
    const float* W0, const float* W1, const float* W2, const float* W3,
    bf16* T0, bf16* T1, bf16* T2, bf16* T3, int K, int N)
{
  const int z = blockIdx.z;
  const float* W = z == 0 ? W0 : z == 1 ? W1 : z == 2 ? W2 : W3;
  bf16* T = z == 0 ? T0 : z == 1 ? T1 : z == 2 ? T2 : T3;
  __shared__ bf16 t[32][33];
  const int k0 = blockIdx.x * 32, n0 = blockIdx.y * 32;
  const int tx = threadIdx.x & 31, ty = threadIdx.x >> 5;
#pragma unroll
  for (int i = 0; i < 4; i++)
    t[ty + i*8][tx] = __float2bfloat16(W[(long)(k0 + ty + i*8)*N + n0 + tx]);
  __syncthreads();
#pragma unroll
  for (int i = 0; i < 4; i++)
    T[(long)(n0 + ty + i*8)*K + k0 + tx] = t[tx][ty + i*8];
}

// ---------------- bf16 transpose with zero-pad: in[R x Cc (ld inLD)] -> out[Cc x outLD] ----------------
__global__ __launch_bounds__(256) void transpose_pad_kernel(
    const bf16* __restrict__ in, bf16* __restrict__ out,
    int R, int Cc, int inLD, int outLD, long inBatch, long outBatch)
{
  in  += (long)blockIdx.z * inBatch;
  out += (long)blockIdx.z * outBatch;
  __shared__ bf16 t[32][33];
  const int r0 = blockIdx.x * 32, c0 = blockIdx.y * 32;
  const int tx = threadIdx.x & 31, ty = threadIdx.x >> 5;
#pragma unroll
  for (int i = 0; i < 4; i++) {
    const int r = r0 + ty + i*8;
    bf16 v = __float2bfloat16(0.0f);
    if (r < R) v = in[(long)r*inLD + c0 + tx];
    t[ty + i*8][tx] = v;
  }
  __syncthreads();
#pragma unroll
  for (int i = 0; i < 4; i++) {
    const int oc = r0 + tx;
    const int orow = c0 + ty + i*8;
    if (oc < outLD) out[(long)orow*outLD + oc] = t[tx][ty + i*8];
  }
}

// ---------------- bias concat (up to 3) ----------------
__global__ __launch_bounds__(256) void concat_bias_kernel(
    const float* a, const float* b, const float* c, int n1, int n2, int n3, float* out)
{
  const int i = blockIdx.x * 256 + threadIdx.x;
  if (i >= n1 + n2 + n3) return;
  out[i] = i < n1 ? a[i] : (i < n1 + n2 ? b[i - n1] : c[i - n1 - n2]);
}

// ---------------- embedding + sinusoidal positional encoding ----------------
__global__ __launch_bounds__(256) void embed_kernel(
    const int* __restrict__ tok, const float* __restrict__ tbl,
    float* __restrict__ xf, bf16* __restrict__ xb)
{
  const int row = blockIdx.x;
  const int s = row & 511;
  const float pos = (float)s;
  const float* te = tbl + (long)tok[row] * 1024;
  const int d0 = threadIdx.x * 4;
  float4 v = *(const float4*)(te + d0);
  float o[4] = {v.x, v.y, v.z, v.w};
#pragma unroll
  for (int k = 0; k < 4; k++) {
    const int d = d0 + k;
    const int i2 = d & ~1;
    const float ang = pos * exp2f((float)i2 * -0.0129762816f);
    o[k] += (d & 1) ? __cosf(ang) : __sinf(ang);
  }
  *(float4*)(xf + (long)row*1024 + d0) = make_float4(o[0], o[1], o[2], o[3]);
#pragma unroll
  for (int k = 0; k < 4; k++) xb[(long)row*1024 + d0 + k] = __float2bfloat16(o[k]);
}

// ---------------- f32 -> bf16 copy ----------------
__global__ __launch_bounds__(256) void cvt_bf16_kernel(const float* __restrict__ in, bf16* __restrict__ out, long n)
{
  long i = (long)blockIdx.x * blockDim.x + threadIdx.x;
  if (i < n) out[i] = __float2bfloat16(in[i]);
}

// ---------------- causal softmax over scores [B*S rows][512] ----------------
__global__ __launch_bounds__(64) void softmax_causal_kernel(
    const float* __restrict__ Sc, bf16* __restrict__ P)
{
  const int row = blockIdx.x;
  const int q = row & 511;
  const float* srow = Sc + (long)row * 512;
  bf16* prow = P + (long)row * 512;
  const int lane = threadIdx.x;
  const float scale = 0.03125f;
  float mx = -1e30f;
  for (int j = lane; j <= q; j += 64) mx = fmaxf(mx, srow[j]);
  mx = wredmax(mx);
  float sum = 0.0f;
  for (int j = lane; j <= q; j += 64) sum += expf((srow[j] - mx) * scale);
  sum = wredsum(sum);
  const float inv = 1.0f / sum;
  for (int j = lane; j < 512; j += 64) {
    float p = (j <= q) ? expf((srow[j] - mx) * scale) * inv : 0.0f;
    prow[j] = __float2bfloat16(p);
  }
}

// ---------------- cross softmax: rows of 197 valid (ld 224) ----------------
__global__ __launch_bounds__(64) void softmax_cross_kernel(
    const float* __restrict__ Sc, bf16* __restrict__ P)
{
  const int row = blockIdx.x;
  const float* srow = Sc + (long)row * 224;
  bf16* prow = P + (long)row * 224;
  const int lane = threadIdx.x;
  const float scale = 0.03125f;
  float mx = -1e30f;
  for (int j = lane; j < 197; j += 64) mx = fmaxf(mx, srow[j]);
  mx = wredmax(mx);
  float sum = 0.0f;
  for (int j = lane; j < 197; j += 64) sum += expf((srow[j] - mx) * scale);
  sum = wredsum(sum);
  const float inv = 1.0f / sum;
  for (int j = lane; j < 224; j += 64) {
    float p = (j < 197) ? expf((srow[j] - mx) * scale) * inv : 0.0f;
    prow[j] = __float2bfloat16(p);
  }
}

// ---------------- add residual + LayerNorm; write f32 (optional) + bf16 ----------------
__global__ __launch_bounds__(256) void add_ln_kernel(
    const float* __restrict__ Acc, const float* __restrict__ Res,
    const float* __restrict__ g, const float* __restrict__ b,
    float* __restrict__ outf, bf16* __restrict__ outb)
{
  const int row = blockIdx.x;
  const float* a = Acc + (long)row * 1024;
  const float* r = Res + (long)row * 1024;
  float vals[4], s = 0.0f, ss = 0.0f;
#pragma unroll
  for (int i = 0; i < 4; i++) {
    const int d = threadIdx.x + i*256;
    const float v = a[d] + r[d];
    vals[i] = v; s += v; ss += v*v;
  }
  s = wredsum(s); ss = wredsum(ss);
  __shared__ float sh[8];
  const int wave = threadIdx.x >> 6, lane = threadIdx.x & 63;
  if (lane == 0) { sh[wave] = s; sh[wave+4] = ss; }
  __syncthreads();
  s  = sh[0] + sh[1] + sh[2] + sh[3];
  ss = sh[4] + sh[5] + sh[6] + sh[7];
  const float mean = s * (1.0f/1024.0f);
  const float var  = ss * (1.0f/1024.0f) - mean*mean;
  const float inv  = rsqrtf(var + 1e-5f);
#pragma unroll
  for (int i = 0; i < 4; i++) {
    const int d = threadIdx.x + i*256;
    const float y = (vals[i] - mean) * inv * g[d] + b[d];
    if (outf) outf[(long)row*1024 + d] = y;
    outb[(long)row*1024 + d] = __float2bfloat16(y);
  }
}

// =======================================================================================
extern "C" void kernel_launch(void* const* d_in, const int* in_sizes, int n_in,
                              void* d_out, int out_size, void* d_ws, size_t ws_size,
                              hipStream_t stream) {
  const int*   tokens = (const int*)  d_in[0];
  const float* img    = (const float*)d_in[1];
  const float* emb    = (const float*)d_in[2];
  const float* Wq1    = (const float*)d_in[3];
  const float* bq1    = (const float*)d_in[4];
  const float* Wk1    = (const float*)d_in[5];
  const float* bk1    = (const float*)d_in[6];
  const float* Wv1    = (const float*)d_in[7];
  const float* bv1    = (const float*)d_in[8];
  const float* g1     = (const float*)d_in[9];
  const float* b1     = (const float*)d_in[10];
  const float* Wq2    = (const float*)d_in[11];
  const float* bq2    = (const float*)d_in[12];
  const float* Wk2    = (const float*)d_in[13];
  const float* bk2    = (const float*)d_in[14];
  const float* Wv2    = (const float*)d_in[15];
  const float* bv2    = (const float*)d_in[16];
  const float* g2     = (const float*)d_in[17];
  const float* b2     = (const float*)d_in[18];
  const float* Wp     = (const float*)d_in[19];
  const float* bp     = (const float*)d_in[20];
  float* out = (float*)d_out;

  const int B = 8, S = 512, D = 1024, DI = 768, NI = 197, NIP = 224, V = 32000;
  const int M = B * S;          // 4096
  const int MI = B * NI;        // 1576

  char* ws = (char*)d_ws;
  size_t off = 0;
  auto alloc = [&](size_t bytes) -> char* {
    char* p = ws + off; off += (bytes + 255) & ~(size_t)255; return p;
  };
  // NOTE: Wq1t/Wk1t/Wv1t contiguous (each 2MB, 256-aligned) -> fused QKV B-matrix [3072][1024].
  //       Wk2t/Wv2t contiguous (each 1.5MB) -> fused KV2 B-matrix [2048][768].
  bf16* Wq1t = (bf16*)alloc((size_t)D*D*2);
  bf16* Wk1t = (bf16*)alloc((size_t)D*D*2);
  bf16* Wv1t = (bf16*)alloc((size_t)D*D*2);
  bf16* Wq2t = (bf16*)alloc((size_t)D*D*2);
  bf16* Wk2t = (bf16*)alloc((size_t)D*DI*2);
  bf16* Wv2t = (bf16*)alloc((size_t)D*DI*2);
  bf16* Wpt  = (bf16*)alloc((size_t)V*D*2);
  float* bqkv= (float*)alloc((size_t)3*D*4);
  float* bkv2= (float*)alloc((size_t)2*D*4);
  float* xf  = (float*)alloc((size_t)M*D*4);
  bf16*  xb  = (bf16*) alloc((size_t)M*D*2);
  bf16*  imgb= (bf16*) alloc((size_t)MI*DI*2);
  bf16*  QKV = (bf16*) alloc((size_t)M*3*D*2);   // [M][3072]: Q | K | V
  bf16*  Vt  = (bf16*) alloc((size_t)M*D*2);
  float* sc1 = (float*)alloc((size_t)B*S*S*4);
  bf16*  P1  = (bf16*) alloc((size_t)B*S*S*2);
  float* ao1 = (float*)alloc((size_t)M*D*4);
  float* x2f = (float*)alloc((size_t)M*D*4);
  bf16*  x2b = (bf16*) alloc((size_t)M*D*2);
  bf16*  Q2  = (bf16*) alloc((size_t)M*D*2);
  bf16*  KV2 = (bf16*) alloc((size_t)MI*2*D*2);  // [MI][2048]: K2 | V2
  bf16*  V2t = (bf16*) alloc((size_t)B*D*NIP*2);
  float* sc2 = (float*)alloc((size_t)B*S*NIP*4);
  bf16*  P2  = (bf16*) alloc((size_t)B*S*NIP*2);
  float* ao2 = (float*)alloc((size_t)M*D*4);
  bf16*  x3b = (bf16*) alloc((size_t)M*D*2);
  (void)ws_size; (void)in_sizes; (void)n_in; (void)out_size;

  // --- weight prep (f32 [K,N] -> bf16 [N,K]) ---
  wprep4_kernel<<<dim3(D/32,  D/32, 4), 256, 0, stream>>>(Wq1, Wk1, Wv1, Wq2, Wq1t, Wk1t, Wv1t, Wq2t, D, D);
  wprep4_kernel<<<dim3(DI/32, D/32, 2), 256, 0, stream>>>(Wk2, Wv2, nullptr, nullptr, Wk2t, Wv2t, nullptr, nullptr, DI, D);
  wprep4_kernel<<<dim3(D/32,  V/32, 1), 256, 0, stream>>>(Wp, nullptr, nullptr, nullptr, Wpt, nullptr, nullptr, nullptr, D, V);
  concat_bias_kernel<<<(3*D+255)/256, 256, 0, stream>>>(bq1, bk1, bv1, D, D, D, bqkv);
  concat_bias_kernel<<<(2*D+255)/256, 256, 0, stream>>>(bk2, bv2, nullptr, D, D, 0, bkv2);

  // --- embed + img convert ---
  embed_kernel<<<M, 256, 0, stream>>>(tokens, emb, xf, xb);
  {
    long n = (long)MI * DI;
    cvt_bf16_kernel<<<(int)((n + 255)/256), 256, 0, stream>>>(img, imgb, n);
  }

  auto gemmF = [&](const bf16* A, const bf16* Bt, float* C, const float* bias,
                   int m, int n, int k, int lda, int ldb, int ldc,
                   long sA, long sB, long sC, int batch) {
    dim3 g((m+127)/128, (n+127)/128, batch);
    gemm_bt_kernel<float><<<g, 256, 0, stream>>>(A, Bt, C, bias, m, n, k, lda, ldb, ldc, sA, sB, sC);
  };
  auto gemmB = [&](const bf16* A, const bf16* Bt, bf16* C, const float* bias,
                   int m, int n, int k, int lda, int ldb, int ldc,
                   long sA, long sB, long sC, int batch) {
    dim3 g((m+127)/128, (n+127)/128, batch);
    gemm_bt_kernel<bf16><<<g, 256, 0, stream>>>(A, Bt, C, bias, m, n, k, lda, ldb, ldc, sA, sB, sC);
  };

  // --- block 1: causal self-attention (fused QKV GEMM via 256^2 kernel: grid 16x12=192) ---
  gemm256_kernel<bf16><<<dim3((M/256)*(3*D/256)), 512, 0, stream>>>(
      xb, Wq1t, QKV, bqkv, M, 3*D, D, D, D, 3*D);
  transpose_pad_kernel<<<dim3(S/32, D/32, B), 256, 0, stream>>>(
      QKV + 2*D, Vt, S, D, 3*D, S, (long)S*3*D, (long)D*S);
  gemmF(QKV, QKV + D, sc1, nullptr, S, S, D, 3*D, 3*D, S, (long)S*3*D, (long)S*3*D, (long)S*S, B);
  softmax_causal_kernel<<<M, 64, 0, stream>>>(sc1, P1);
  gemmF(P1, Vt, ao1, nullptr, S, D, S, S, S, D, (long)S*S, (long)D*S, (long)S*D, B);
  add_ln_kernel<<<M, 256, 0, stream>>>(ao1, xf, g1, b1, x2f, x2b);

  // --- block 2: cross-attention over image tokens (fused K2V2 GEMM: N=2048) ---
  gemmB(x2b, Wq2t, Q2, bq2, M, D, D, D, D, D, 0, 0, 0, 1);
  gemmB(imgb, Wk2t, KV2, bkv2, MI, 2*D, DI, DI, DI, 2*D, 0, 0, 0, 1);
  transpose_pad_kernel<<<dim3((NIP+31)/32, D/32, B), 256, 0, stream>>>(
      KV2 + D, V2t, NI, D, 2*D, NIP, (long)NI*2*D, (long)D*NIP);
  gemmF(Q2, KV2, sc2, nullptr, S, NI, D, D, 2*D, NIP, (long)S*D, (long)NI*2*D, (long)S*NIP, B);
  softmax_cross_kernel<<<M, 64, 0, stream>>>(sc2, P2);
  gemmF(P2, V2t, ao2, nullptr, S, D, NIP, NIP, NIP, D, (long)S*NIP, (long)D*NIP, (long)S*D, B);
  add_ln_kernel<<<M, 256, 0, stream>>>(ao2, x2f, g2, b2, nullptr, x3b);

  // --- vocab projection: ring-2 2-blocks/CU 256^2 kernel (grid 16x125 = 2000 blocks) ---
  gemm256_kernel<float><<<dim3((M/256)*(V/256)), 512, 0, stream>>>(
      x3b, Wpt, out, bp, M, V, D, D, D, V);
}

// Round 10
// 669.901 us; speedup vs baseline: 1.0978x; 1.0978x over previous
//
#include <hip/hip_runtime.h>
#include <hip/hip_bf16.h>

// Decoder forward: embed+posenc -> causal self-attn -> LN -> cross-attn(img) -> LN -> vocab proj
// B=8 S=512 D=1024 DI=768 NI=197(pad 224) V=32000. GEMMs bf16 MFMA (16x16x32), f32 accum.
// R10: vocab reverted to R8 ring-4 (R9's ring-2 lost: occupancy never rose, dur 364->400).
//      Small GEMMs (gemm_bt) -> ring-2 double-buffered, 32KB LDS (up to 5 blocks/CU),
//      1 barrier/K-step: hides load latency for the latency-bound tail. Q2 -> gemm256.

#define DEV __device__ __forceinline__

typedef __bf16 bf16x8 __attribute__((ext_vector_type(8)));
typedef float f32x4 __attribute__((ext_vector_type(4)));
typedef unsigned int u32;
typedef __hip_bfloat16 bf16;

DEV void llds16(const void* g, void* l) {
  __builtin_amdgcn_global_load_lds((const __attribute__((address_space(1))) u32*)g,
                                   (__attribute__((address_space(3))) u32*)l, 16, 0, 0);
}

DEV float wredsum(float v){
#pragma unroll
  for (int o = 32; o; o >>= 1) v += __shfl_xor(v, o, 64);
  return v;
}
DEV float wredmax(float v){
#pragma unroll
  for (int o = 32; o; o >>= 1) v = fmaxf(v, __shfl_xor(v, o, 64));
  return v;
}

DEV void store_out(float* p, float v){ *p = v; }
DEV void store_out(bf16* p, float v){ *p = __float2bfloat16(v); }

// ================= big GEMM: C[M,N] = A[M,K] @ Bt[N,K]^T + bias =================
// R8 ring-4 structure (vocab best: 364us): 256x256 tile, BK=32, 8 waves, 128KiB LDS,
// stage t+3 during t, counted vmcnt(8). T1/T2/T5. M%256==0, N%256==0, K%32==0, K>=96.
template<typename OutT>
__global__ __launch_bounds__(512, 1) void gemm256_kernel(
    const bf16* __restrict__ A, const bf16* __restrict__ Bt, OutT* __restrict__ C,
    const float* __restrict__ bias, int M, int N, int K, int lda, int ldb, int ldc)
{
  __shared__ alignas(16) char lds[131072];
  const int tid  = threadIdx.x;
  const int wave = tid >> 6, lane = tid & 63;
  const int lo = lane & 15, hi = lane >> 4;
  const int hi2 = hi ^ ((lo >> 1) & 3);            // swizzled 16B slot for ds_read
  const int wr = wave >> 2, wc = wave & 3;
  const int koff = (((lane & 3) ^ ((lane >> 3) & 3)) << 3);  // pre-swizzled global k (write side)

  const int nbx = M >> 8;
  const int nwg = nbx * (N >> 8);
  int id = blockIdx.x;
  int g = (nwg & 7) ? id : ((id & 7) * (nwg >> 3) + (id >> 3));
  const int row0 = (g % nbx) * 256, col0 = (g / nbx) * 256;
  const int NT = K >> 5;
  const int srow = lane >> 2;

  auto stageA = [&](int t) {
    char* base = lds + (t & 3) * 32768;
    const int kk = (t << 5) + koff;
#pragma unroll
    for (int j = 0; j < 2; j++) {
      const int seg = j * 8 + wave;
      llds16(A + (long)(row0 + seg * 16 + srow) * lda + kk, base + seg * 1024);
    }
  };
  auto stageB = [&](int t) {
    char* base = lds + (t & 3) * 32768 + 16384;
    const int kk = (t << 5) + koff;
#pragma unroll
    for (int j = 0; j < 2; j++) {
      const int seg = j * 8 + wave;
      llds16(Bt + (long)(col0 + seg * 16 + srow) * ldb + kk, base + seg * 1024);
    }
  };

  f32x4 acc[8][4] = {};

  stageA(0); stageB(0);
  stageA(1); stageB(1);
  stageA(2); stageB(2);
  asm volatile("s_waitcnt vmcnt(8)" ::: "memory");
  __builtin_amdgcn_s_barrier();
  asm volatile("" ::: "memory");

  for (int t = 0; t < NT; t++) {
    char* As = lds + (t & 3) * 32768;
    char* Bs = As + 16384;
    bf16x8 af[4], bfv[4];
    // phase 1: frags A0-3 + B0-3, stage A(t+3), MFMA quadrant 0
#pragma unroll
    for (int m = 0; m < 4; m++)
      af[m] = *(const bf16x8*)(As + ((wr * 128 + m * 16 + lo) << 6) + (hi2 << 4));
#pragma unroll
    for (int n = 0; n < 4; n++)
      bfv[n] = *(const bf16x8*)(Bs + ((wc * 64 + n * 16 + lo) << 6) + (hi2 << 4));
    if (t + 3 < NT) stageA(t + 3);
    __builtin_amdgcn_s_setprio(1);
#pragma unroll
    for (int m = 0; m < 4; m++)
#pragma unroll
      for (int n = 0; n < 4; n++)
        acc[m][n] = __builtin_amdgcn_mfma_f32_16x16x32_bf16(af[m], bfv[n], acc[m][n], 0, 0, 0);
    __builtin_amdgcn_s_setprio(0);
    asm volatile("" ::: "memory");
    __builtin_amdgcn_s_barrier();
    asm volatile("" ::: "memory");
    // phase 2: frags A4-7, stage B(t+3), MFMA quadrant 1
#pragma unroll
    for (int m = 0; m < 4; m++)
      af[m] = *(const bf16x8*)(As + ((wr * 128 + (m + 4) * 16 + lo) << 6) + (hi2 << 4));
    if (t + 3 < NT) stageB(t + 3);
    __builtin_amdgcn_s_setprio(1);
#pragma unroll
    for (int m = 0; m < 4; m++)
#pragma unroll
      for (int n = 0; n < 4; n++)
        acc[m + 4][n] = __builtin_amdgcn_mfma_f32_16x16x32_bf16(af[m], bfv[n], acc[m + 4][n], 0, 0, 0);
    __builtin_amdgcn_s_setprio(0);
    if (t < NT - 3)       asm volatile("s_waitcnt vmcnt(8)" ::: "memory");
    else if (t == NT - 3) asm volatile("s_waitcnt vmcnt(4)" ::: "memory");
    else                  asm volatile("s_waitcnt vmcnt(0)" ::: "memory");
    __builtin_amdgcn_s_barrier();
    asm volatile("" ::: "memory");
  }

#pragma unroll
  for (int m = 0; m < 8; m++) {
    const int r = row0 + wr * 128 + m * 16 + hi * 4;
#pragma unroll
    for (int n = 0; n < 4; n++) {
      const int c = col0 + wc * 64 + n * 16 + lo;
      const float bb = bias ? bias[c] : 0.0f;
#pragma unroll
      for (int j = 0; j < 4; j++)
        store_out(&C[(long)(r + j) * ldc + c], acc[m][n][j] + bb);
    }
  }
}

// ---------------- small GEMM: C[M,N] = A[M,K] @ Bt[N,K]^T (+bias[N]) ----------------
// R10: 128x128 tile, BK=32, 4 waves (2x2), ring-2 double-buffered (32KB LDS -> up to
// 5 blocks/CU), stage t+1 before tile-t compute, ONE barrier/K-step. T2-swizzled,
// bounds-clamped staging + guarded stores (general shapes). Requires K%32==0.
template<typename OutT>
__global__ __launch_bounds__(256) void gemm_bt_kernel(
    const bf16* __restrict__ A, const bf16* __restrict__ Bt, OutT* __restrict__ C,
    const float* __restrict__ bias, int M, int N, int K,
    int lda, int ldb, int ldc, long sA, long sB, long sC)
{
  A  += (long)blockIdx.z * sA;
  Bt += (long)blockIdx.z * sB;
  C  += (long)blockIdx.z * sC;
  __shared__ alignas(16) char lds[32768];   // 2 slots x (A 8KB + B 8KB)
  const int tid = threadIdx.x;
  const int wave = tid >> 6, lane = tid & 63;
  const int lo = lane & 15, hi = lane >> 4;
  const int hi2 = hi ^ ((lo >> 1) & 3);
  const int wr = wave >> 1, wc = wave & 1;
  const int row0 = blockIdx.x * 128, col0 = blockIdx.y * 128;
  const int srow  = lane >> 2;
  const int skoff = (((lane & 3) ^ ((lane >> 3) & 3)) << 3);
  const int NT = K >> 5;

  auto stage = [&](int t) {
    char* base = lds + (t & 1) * 16384;
    const int kk = (t << 5) + skoff;
#pragma unroll
    for (int c = 0; c < 2; ++c) {
      const int seg = c*4 + wave;
      int ra = row0 + seg*16 + srow; ra = ra < M ? ra : M-1;
      llds16(A + (long)ra*lda + kk, base + seg*1024);
      int rb = col0 + seg*16 + srow; rb = rb < N ? rb : N-1;
      llds16(Bt + (long)rb*ldb + kk, base + 8192 + seg*1024);
    }
  };

  f32x4 acc[4][4] = {};

  stage(0);
  asm volatile("s_waitcnt vmcnt(0)" ::: "memory");
  __builtin_amdgcn_s_barrier();
  __builtin_amdgcn_sched_barrier(0);

  for (int t = 0; t < NT; t++) {
    const char* As = lds + (t & 1) * 16384;
    const char* Bs = As + 8192;
    if (t + 1 < NT) stage(t + 1);   // lands during this tile's reads + MFMA
    bf16x8 af[4], bfv[4];
#pragma unroll
    for (int m = 0; m < 4; m++)
      af[m] = *(const bf16x8*)(As + ((wr*64 + m*16 + lo) << 6) + (hi2 << 4));
#pragma unroll
    for (int n = 0; n < 4; n++)
      bfv[n] = *(const bf16x8*)(Bs + ((wc*64 + n*16 + lo) << 6) + (hi2 << 4));
    __builtin_amdgcn_s_setprio(1);
#pragma unroll
    for (int m = 0; m < 4; m++)
#pragma unroll
      for (int n = 0; n < 4; n++)
        acc[m][n] = __builtin_amdgcn_mfma_f32_16x16x32_bf16(af[m], bfv[n], acc[m][n], 0, 0, 0);
    __builtin_amdgcn_s_setprio(0);
    __builtin_amdgcn_sched_barrier(0);
    asm volatile("s_waitcnt vmcnt(0)" ::: "memory");
    __builtin_amdgcn_sched_barrier(0);
    __builtin_amdgcn_s_barrier();
    __builtin_amdgcn_sched_barrier(0);
  }

#pragma unroll
  for (int m = 0; m < 4; m++) {
    const int rbase = row0 + wr*64 + m*16 + hi*4;
#pragma unroll
    for (int n = 0; n < 4; n++) {
      const int cc = col0 + wc*64 + n*16 + lo;
      if (cc >= N) continue;
      const float bb = bias ? bias[cc] : 0.0f;
#pragma unroll
      for (int j = 0; j < 4; j++) {
        const int rr = rbase + j;
        if (rr < M) store_out(&C[(long)rr*ldc + cc], acc[m][n][j] + bb);
      }
    }
  }
}

// ---------------- weight prep: W[K,N] f32 -> Wt[N,K] bf16, z-indexed up to 4 pairs ----------------
__global__ __launch_bounds__(256) void wprep4_kernel(
    const float* W0, const float* W1, const float* W2, const float* W3,
    bf16* T0, bf16* T1, bf16* T2, bf16* T3, int K, int N)
{
  const int z = blockIdx.z;
  const float* W = z == 0 ? W0 : z == 1 ? W1 : z == 2 ? W2 : W3;
  bf16* T = z == 0 ? T0 : z == 1 ? T1 : z == 2 ? T2 : T3;
  __shared__ bf16 t[32][33];
  const int k0 = blockIdx.x * 32, n0 = blockIdx.y * 32;
  const int tx = threadIdx.x & 31, ty = threadIdx.x >> 5;
#pragma unroll
  for (int i = 0; i < 4; i++)
    t[ty + i*8][tx] = __float2bfloat16(W[(long)(k0 + ty + i*8)*N + n0 + tx]);
  __syncthreads();
#pragma unroll
  for (int i = 0; i < 4; i++)
    T[(long)(n0 + ty + i*8)*K + k0 + tx] = t[tx][ty + i*8];
}

// ---------------- bf16 transpose with zero-pad: in[R x Cc (ld inLD)] -> out[Cc x outLD] ----------------
__global__ __launch_bounds__(256) void transpose_pad_kernel(
    const bf16* __restrict__ in, bf16* __restrict__ out,
    int R, int Cc, int inLD, int outLD, long inBatch, long outBatch)
{
  in  += (long)blockIdx.z * inBatch;
  out += (long)blockIdx.z * outBatch;
  __shared__ bf16 t[32][33];
  const int r0 = blockIdx.x * 32, c0 = blockIdx.y * 32;
  const int tx = threadIdx.x & 31, ty = threadIdx.x >> 5;
#pragma unroll
  for (int i = 0; i < 4; i++) {
    const int r = r0 + ty + i*8;
    bf16 v = __float2bfloat16(0.0f);
    if (r < R) v = in[(long)r*inLD + c0 + tx];
    t[ty + i*8][tx] = v;
  }
  __syncthreads();
#pragma unroll
  for (int i = 0; i < 4; i++) {
    const int oc = r0 + tx;
    const int orow = c0 + ty + i*8;
    if (oc < outLD) out[(long)orow*outLD + oc] = t[tx][ty + i*8];
  }
}

// ---------------- bias concat (up to 3) ----------------
__global__ __launch_bounds__(256) void concat_bias_kernel(
    const float* a, const float* b, const float* c, int n1, int n2, int n3, float* out)
{
  const int i = blockIdx.x * 256 + threadIdx.x;
  if (i >= n1 + n2 + n3) return;
  out[i] = i < n1 ? a[i] : (i < n1 + n2 ? b[i - n1] : c[i - n1 - n2]);
}

// ---------------- embedding + sinusoidal positional encoding ----------------
__global__ __launch_bounds__(256) void embed_kernel(
    const int* __restrict__ tok, const float* __restrict__ tbl,
    float* __restrict__ xf, bf16* __restrict__ xb)
{
  const int row = blockIdx.x;
  const int s = row & 511;
  const float pos = (float)s;
  const float* te = tbl + (long)tok[row] * 1024;
  const int d0 = threadIdx.x * 4;
  float4 v = *(const float4*)(te + d0);
  float o[4] = {v.x, v.y, v.z, v.w};
#pragma unroll
  for (int k = 0; k < 4; k++) {
    const int d = d0 + k;
    const int i2 = d & ~1;
    const float ang = pos * exp2f((float)i2 * -0.0129762816f);
    o[k] += (d & 1) ? __cosf(ang) : __sinf(ang);
  }
  *(float4*)(xf + (long)row*1024 + d0) = make_float4(o[0], o[1], o[2], o[3]);
#pragma unroll
  for (int k = 0; k < 4; k++) xb[(long)row*1024 + d0 + k] = __float2bfloat16(o[k]);
}

// ---------------- f32 -> bf16 copy ----------------
__global__ __launch_bounds__(256) void cvt_bf16_kernel(const float* __restrict__ in, bf16* __restrict__ out, long n)
{
  long i = (long)blockIdx.x * blockDim.x + threadIdx.x;
  if (i < n) out[i] = __float2bfloat16(in[i]);
}

// ---------------- causal softmax over scores [B*S rows][512] ----------------
__global__ __launch_bounds__(64) void softmax_causal_kernel(
    const float* __restrict__ Sc, bf16* __restrict__ P)
{
  const int row = blockIdx.x;
  const int q = row & 511;
  const float* srow = Sc + (long)row * 512;
  bf16* prow = P + (long)row * 512;
  const int lane = threadIdx.x;
  const float scale = 0.03125f;
  float mx = -1e30f;
  for (int j = lane; j <= q; j += 64) mx = fmaxf(mx, srow[j]);
  mx = wredmax(mx);
  float sum = 0.0f;
  for (int j = lane; j <= q; j += 64) sum += expf((srow[j] - mx) * scale);
  sum = wredsum(sum);
  const float inv = 1.0f / sum;
  for (int j = lane; j < 512; j += 64) {
    float p = (j <= q) ? expf((srow[j] - mx) * scale) * inv : 0.0f;
    prow[j] = __float2bfloat16(p);
  }
}

// ---------------- cross softmax: rows of 197 valid (ld 224) ----------------
__global__ __launch_bounds__(64) void softmax_cross_kernel(
    const float* __restrict__ Sc, bf16* __restrict__ P)
{
  const int row = blockIdx.x;
  const float* srow = Sc + (long)row * 224;
  bf16* prow = P + (long)row * 224;
  const int lane = threadIdx.x;
  const float scale = 0.03125f;
  float mx = -1e30f;
  for (int j = lane; j < 197; j += 64) mx = fmaxf(mx, srow[j]);
  mx = wredmax(mx);
  float sum = 0.0f;
  for (int j = lane; j < 197; j += 64) sum += expf((srow[j] - mx) * scale);
  sum = wredsum(sum);
  const float inv = 1.0f / sum;
  for (int j = lane; j < 224; j += 64) {
    float p = (j < 197) ? expf((srow[j] - mx) * scale) * inv : 0.0f;
    prow[j] = __float2bfloat16(p);
  }
}

// ---------------- add residual + LayerNorm; write f32 (optional) + bf16 ----------------
__global__ __launch_bounds__(256) void add_ln_kernel(
    const float* __restrict__ Acc, const float* __restrict__ Res,
    const float* __restrict__ g, const float* __restrict__ b,
    float* __restrict__ outf, bf16* __restrict__ outb)
{
  const int row = blockIdx.x;
  const float* a = Acc + (long)row * 1024;
  const float* r = Res + (long)row * 1024;
  float vals[4], s = 0.0f, ss = 0.0f;
#pragma unroll
  for (int i = 0; i < 4; i++) {
    const int d = threadIdx.x + i*256;
    const float v = a[d] + r[d];
    vals[i] = v; s += v; ss += v*v;
  }
  s = wredsum(s); ss = wredsum(ss);
  __shared__ float sh[8];
  const int wave = threadIdx.x >> 6, lane = threadIdx.x & 63;
  if (lane == 0) { sh[wave] = s; sh[wave+4] = ss; }
  __syncthreads();
  s  = sh[0] + sh[1] + sh[2] + sh[3];
  ss = sh[4] + sh[5] + sh[6] + sh[7];
  const float mean = s * (1.0f/1024.0f);
  const float var  = ss * (1.0f/1024.0f) - mean*mean;
  const float inv  = rsqrtf(var + 1e-5f);
#pragma unroll
  for (int i = 0; i < 4; i++) {
    const int d = threadIdx.x + i*256;
    const float y = (vals[i] - mean) * inv * g[d] + b[d];
    if (outf) outf[(long)row*1024 + d] = y;
    outb[(long)row*1024 + d] = __float2bfloat16(y);
  }
}

// =======================================================================================
extern "C" void kernel_launch(void* const* d_in, const int* in_sizes, int n_in,
                              void* d_out, int out_size, void* d_ws, size_t ws_size,
                              hipStream_t stream) {
  const int*   tokens = (const int*)  d_in[0];
  const float* img    = (const float*)d_in[1];
  const float* emb    = (const float*)d_in[2];
  const float* Wq1    = (const float*)d_in[3];
  const float* bq1    = (const float*)d_in[4];
  const float* Wk1    = (const float*)d_in[5];
  const float* bk1    = (const float*)d_in[6];
  const float* Wv1    = (const float*)d_in[7];
  const float* bv1    = (const float*)d_in[8];
  const float* g1     = (const float*)d_in[9];
  const float* b1     = (const float*)d_in[10];
  const float* Wq2    = (const float*)d_in[11];
  const float* bq2    = (const float*)d_in[12];
  const float* Wk2    = (const float*)d_in[13];
  const float* bk2    = (const float*)d_in[14];
  const float* Wv2    = (const float*)d_in[15];
  const float* bv2    = (const float*)d_in[16];
  const float* g2     = (const float*)d_in[17];
  const float* b2     = (const float*)d_in[18];
  const float* Wp     = (const float*)d_in[19];
  const float* bp     = (const float*)d_in[20];
  float* out = (float*)d_out;

  const int B = 8, S = 512, D = 1024, DI = 768, NI = 197, NIP = 224, V = 32000;
  const int M = B * S;          // 4096
  const int MI = B * NI;        // 1576

  char* ws = (char*)d_ws;
  size_t off = 0;
  auto alloc = [&](size_t bytes) -> char* {
    char* p = ws + off; off += (bytes + 255) & ~(size_t)255; return p;
  };
  // NOTE: Wq1t/Wk1t/Wv1t contiguous (each 2MB, 256-aligned) -> fused QKV B-matrix [3072][1024].
  //       Wk2t/Wv2t contiguous (each 1.5MB) -> fused KV2 B-matrix [2048][768].
  bf16* Wq1t = (bf16*)alloc((size_t)D*D*2);
  bf16* Wk1t = (bf16*)alloc((size_t)D*D*2);
  bf16* Wv1t = (bf16*)alloc((size_t)D*D*2);
  bf16* Wq2t = (bf16*)alloc((size_t)D*D*2);
  bf16* Wk2t = (bf16*)alloc((size_t)D*DI*2);
  bf16* Wv2t = (bf16*)alloc((size_t)D*DI*2);
  bf16* Wpt  = (bf16*)alloc((size_t)V*D*2);
  float* bqkv= (float*)alloc((size_t)3*D*4);
  float* bkv2= (float*)alloc((size_t)2*D*4);
  float* xf  = (float*)alloc((size_t)M*D*4);
  bf16*  xb  = (bf16*) alloc((size_t)M*D*2);
  bf16*  imgb= (bf16*) alloc((size_t)MI*DI*2);
  bf16*  QKV = (bf16*) alloc((size_t)M*3*D*2);   // [M][3072]: Q | K | V
  bf16*  Vt  = (bf16*) alloc((size_t)M*D*2);
  float* sc1 = (float*)alloc((size_t)B*S*S*4);
  bf16*  P1  = (bf16*) alloc((size_t)B*S*S*2);
  float* ao1 = (float*)alloc((size_t)M*D*4);
  float* x2f = (float*)alloc((size_t)M*D*4);
  bf16*  x2b = (bf16*) alloc((size_t)M*D*2);
  bf16*  Q2  = (bf16*) alloc((size_t)M*D*2);
  bf16*  KV2 = (bf16*) alloc((size_t)MI*2*D*2);  // [MI][2048]: K2 | V2
  bf16*  V2t = (bf16*) alloc((size_t)B*D*NIP*2);
  float* sc2 = (float*)alloc((size_t)B*S*NIP*4);
  bf16*  P2  = (bf16*) alloc((size_t)B*S*NIP*2);
  float* ao2 = (float*)alloc((size_t)M*D*4);
  bf16*  x3b = (bf16*) alloc((size_t)M*D*2);
  (void)ws_size; (void)in_sizes; (void)n_in; (void)out_size;

  // --- weight prep (f32 [K,N] -> bf16 [N,K]) ---
  wprep4_kernel<<<dim3(D/32,  D/32, 4), 256, 0, stream>>>(Wq1, Wk1, Wv1, Wq2, Wq1t, Wk1t, Wv1t, Wq2t, D, D);
  wprep4_kernel<<<dim3(DI/32, D/32, 2), 256, 0, stream>>>(Wk2, Wv2, nullptr, nullptr, Wk2t, Wv2t, nullptr, nullptr, DI, D);
  wprep4_kernel<<<dim3(D/32,  V/32, 1), 256, 0, stream>>>(Wp, nullptr, nullptr, nullptr, Wpt, nullptr, nullptr, nullptr, D, V);
  concat_bias_kernel<<<(3*D+255)/256, 256, 0, stream>>>(bq1, bk1, bv1, D, D, D, bqkv);
  concat_bias_kernel<<<(2*D+255)/256, 256, 0, stream>>>(bk2, bv2, nullptr, D, D, 0, bkv2);

  // --- embed + img convert ---
  embed_kernel<<<M, 256, 0, stream>>>(tokens, emb, xf, xb);
  {
    long n = (long)MI * DI;
    cvt_bf16_kernel<<<(int)((n + 255)/256), 256, 0, stream>>>(img, imgb, n);
  }

  auto gemmF = [&](const bf16* A, const bf16* Bt, float* C, const float* bias,
                   int m, int n, int k, int lda, int ldb, int ldc,
                   long sA, long sB, long sC, int batch) {
    dim3 g((m+127)/128, (n+127)/128, batch);
    gemm_bt_kernel<float><<<g, 256, 0, stream>>>(A, Bt, C, bias, m, n, k, lda, ldb, ldc, sA, sB, sC);
  };
  auto gemmB = [&](const bf16* A, const bf16* Bt, bf16* C, const float* bias,
                   int m, int n, int k, int lda, int ldb, int ldc,
                   long sA, long sB, long sC, int batch) {
    dim3 g((m+127)/128, (n+127)/128, batch);
    gemm_bt_kernel<bf16><<<g, 256, 0, stream>>>(A, Bt, C, bias, m, n, k, lda, ldb, ldc, sA, sB, sC);
  };

  // --- block 1: causal self-attention (fused QKV GEMM via 256^2 kernel: grid 16x12=192) ---
  gemm256_kernel<bf16><<<dim3((M/256)*(3*D/256)), 512, 0, stream>>>(
      xb, Wq1t, QKV, bqkv, M, 3*D, D, D, D, 3*D);
  transpose_pad_kernel<<<dim3(S/32, D/32, B), 256, 0, stream>>>(
      QKV + 2*D, Vt, S, D, 3*D, S, (long)S*3*D, (long)D*S);
  gemmF(QKV, QKV + D, sc1, nullptr, S, S, D, 3*D, 3*D, S, (long)S*3*D, (long)S*3*D, (long)S*S, B);
  softmax_causal_kernel<<<M, 64, 0, stream>>>(sc1, P1);
  gemmF(P1, Vt, ao1, nullptr, S, D, S, S, S, D, (long)S*S, (long)D*S, (long)S*D, B);
  add_ln_kernel<<<M, 256, 0, stream>>>(ao1, xf, g1, b1, x2f, x2b);

  // --- block 2: cross-attention over image tokens (Q2 via 256^2; fused K2V2 GEMM N=2048) ---
  gemm256_kernel<bf16><<<dim3((M/256)*(D/256)), 512, 0, stream>>>(
      x2b, Wq2t, Q2, bq2, M, D, D, D, D, D);
  gemmB(imgb, Wk2t, KV2, bkv2, MI, 2*D, DI, DI, DI, 2*D, 0, 0, 0, 1);
  transpose_pad_kernel<<<dim3((NIP+31)/32, D/32, B), 256, 0, stream>>>(
      KV2 + D, V2t, NI, D, 2*D, NIP, (long)NI*2*D, (long)D*NIP);
  gemmF(Q2, KV2, sc2, nullptr, S, NI, D, D, 2*D, NIP, (long)S*D, (long)NI*2*D, (long)S*NIP, B);
  softmax_cross_kernel<<<M, 64, 0, stream>>>(sc2, P2);
  gemmF(P2, V2t, ao2, nullptr, S, D, NIP, NIP, NIP, D, (long)S*NIP, (long)D*NIP, (long)S*D, B);
  add_ln_kernel<<<M, 256, 0, stream>>>(ao2, x2f, g2, b2, nullptr, x3b);

  // --- vocab projection: R8 ring-4 256^2 kernel (grid 16x125 = 2000 blocks) ---
  gemm256_kernel<float><<<dim3((M/256)*(V/256)), 512, 0, stream>>>(
      x3b, Wpt, out, bp, M, V, D, D, D, V);
}

// Round 11
// 655.764 us; speedup vs baseline: 1.1215x; 1.0216x over previous
//
#include <hip/hip_runtime.h>
#include <hip/hip_bf16.h>

// Decoder forward: embed+posenc -> causal self-attn -> LN -> cross-attn(img) -> LN -> vocab proj
// B=8 S=512 D=1024 DI=768 NI=197(pad 224) V=32000. GEMMs bf16 MFMA (16x16x32), f32 accum.
// R11: algorithmic tail cuts -- causal block-skip in sc1 (grid 16->10/batch), K-truncation
//      in PV1 (Keff=row0+128), bf16 residual stream (drop f32 xf/x2f/ao1/ao2).
//      Vocab GEMM unchanged from R10 (ring-4 256^2, ~365us plateau).

#define DEV __device__ __forceinline__

typedef __bf16 bf16x8 __attribute__((ext_vector_type(8)));
typedef float f32x4 __attribute__((ext_vector_type(4)));
typedef unsigned int u32;
typedef __hip_bfloat16 bf16;

DEV void llds16(const void* g, void* l) {
  __builtin_amdgcn_global_load_lds((const __attribute__((address_space(1))) u32*)g,
                                   (__attribute__((address_space(3))) u32*)l, 16, 0, 0);
}

DEV float wredsum(float v){
#pragma unroll
  for (int o = 32; o; o >>= 1) v += __shfl_xor(v, o, 64);
  return v;
}
DEV float wredmax(float v){
#pragma unroll
  for (int o = 32; o; o >>= 1) v = fmaxf(v, __shfl_xor(v, o, 64));
  return v;
}

DEV float b2f(unsigned short x){ return __uint_as_float((u32)x << 16); }

DEV void store_out(float* p, float v){ *p = v; }
DEV void store_out(bf16* p, float v){ *p = __float2bfloat16(v); }

// ================= big GEMM: C[M,N] = A[M,K] @ Bt[N,K]^T + bias =================
// R8 ring-4 structure (vocab best: ~365us): 256x256 tile, BK=32, 8 waves, 128KiB LDS,
// stage t+3 during t, counted vmcnt(8). T1/T2/T5. M%256==0, N%256==0, K%32==0, K>=96.
template<typename OutT>
__global__ __launch_bounds__(512, 1) void gemm256_kernel(
    const bf16* __restrict__ A, const bf16* __restrict__ Bt, OutT* __restrict__ C,
    const float* __restrict__ bias, int M, int N, int K, int lda, int ldb, int ldc)
{
  __shared__ alignas(16) char lds[131072];
  const int tid  = threadIdx.x;
  const int wave = tid >> 6, lane = tid & 63;
  const int lo = lane & 15, hi = lane >> 4;
  const int hi2 = hi ^ ((lo >> 1) & 3);            // swizzled 16B slot for ds_read
  const int wr = wave >> 2, wc = wave & 3;
  const int koff = (((lane & 3) ^ ((lane >> 3) & 3)) << 3);  // pre-swizzled global k (write side)

  const int nbx = M >> 8;
  const int nwg = nbx * (N >> 8);
  int id = blockIdx.x;
  int g = (nwg & 7) ? id : ((id & 7) * (nwg >> 3) + (id >> 3));
  const int row0 = (g % nbx) * 256, col0 = (g / nbx) * 256;
  const int NT = K >> 5;
  const int srow = lane >> 2;

  auto stageA = [&](int t) {
    char* base = lds + (t & 3) * 32768;
    const int kk = (t << 5) + koff;
#pragma unroll
    for (int j = 0; j < 2; j++) {
      const int seg = j * 8 + wave;
      llds16(A + (long)(row0 + seg * 16 + srow) * lda + kk, base + seg * 1024);
    }
  };
  auto stageB = [&](int t) {
    char* base = lds + (t & 3) * 32768 + 16384;
    const int kk = (t << 5) + koff;
#pragma unroll
    for (int j = 0; j < 2; j++) {
      const int seg = j * 8 + wave;
      llds16(Bt + (long)(col0 + seg * 16 + srow) * ldb + kk, base + seg * 1024);
    }
  };

  f32x4 acc[8][4] = {};

  stageA(0); stageB(0);
  stageA(1); stageB(1);
  stageA(2); stageB(2);
  asm volatile("s_waitcnt vmcnt(8)" ::: "memory");
  __builtin_amdgcn_s_barrier();
  asm volatile("" ::: "memory");

  for (int t = 0; t < NT; t++) {
    char* As = lds + (t & 3) * 32768;
    char* Bs = As + 16384;
    bf16x8 af[4], bfv[4];
    // phase 1: frags A0-3 + B0-3, stage A(t+3), MFMA quadrant 0
#pragma unroll
    for (int m = 0; m < 4; m++)
      af[m] = *(const bf16x8*)(As + ((wr * 128 + m * 16 + lo) << 6) + (hi2 << 4));
#pragma unroll
    for (int n = 0; n < 4; n++)
      bfv[n] = *(const bf16x8*)(Bs + ((wc * 64 + n * 16 + lo) << 6) + (hi2 << 4));
    if (t + 3 < NT) stageA(t + 3);
    __builtin_amdgcn_s_setprio(1);
#pragma unroll
    for (int m = 0; m < 4; m++)
#pragma unroll
      for (int n = 0; n < 4; n++)
        acc[m][n] = __builtin_amdgcn_mfma_f32_16x16x32_bf16(af[m], bfv[n], acc[m][n], 0, 0, 0);
    __builtin_amdgcn_s_setprio(0);
    asm volatile("" ::: "memory");
    __builtin_amdgcn_s_barrier();
    asm volatile("" ::: "memory");
    // phase 2: frags A4-7, stage B(t+3), MFMA quadrant 1
#pragma unroll
    for (int m = 0; m < 4; m++)
      af[m] = *(const bf16x8*)(As + ((wr * 128 + (m + 4) * 16 + lo) << 6) + (hi2 << 4));
    if (t + 3 < NT) stageB(t + 3);
    __builtin_amdgcn_s_setprio(1);
#pragma unroll
    for (int m = 0; m < 4; m++)
#pragma unroll
      for (int n = 0; n < 4; n++)
        acc[m + 4][n] = __builtin_amdgcn_mfma_f32_16x16x32_bf16(af[m], bfv[n], acc[m + 4][n], 0, 0, 0);
    __builtin_amdgcn_s_setprio(0);
    if (t < NT - 3)       asm volatile("s_waitcnt vmcnt(8)" ::: "memory");
    else if (t == NT - 3) asm volatile("s_waitcnt vmcnt(4)" ::: "memory");
    else                  asm volatile("s_waitcnt vmcnt(0)" ::: "memory");
    __builtin_amdgcn_s_barrier();
    asm volatile("" ::: "memory");
  }

#pragma unroll
  for (int m = 0; m < 8; m++) {
    const int r = row0 + wr * 128 + m * 16 + hi * 4;
#pragma unroll
    for (int n = 0; n < 4; n++) {
      const int c = col0 + wc * 64 + n * 16 + lo;
      const float bb = bias ? bias[c] : 0.0f;
#pragma unroll
      for (int j = 0; j < 4; j++)
        store_out(&C[(long)(r + j) * ldc + c], acc[m][n][j] + bb);
    }
  }
}

// ---------------- small GEMM: C[M,N] = A[M,K] @ Bt[N,K]^T (+bias[N]) ----------------
// 128x128 tile, BK=32, 4 waves, ring-2 double-buffered (32KB LDS), 1 barrier/K-step.
// tri: blockIdx.x linearizes the lower-triangle (bx>=by) of an nb x nb block grid.
// kcausal: Keff = min(K, row0+128) (for PV with causal-zeroed P columns).
template<typename OutT>
__global__ __launch_bounds__(256) void gemm_bt_kernel(
    const bf16* __restrict__ A, const bf16* __restrict__ Bt, OutT* __restrict__ C,
    const float* __restrict__ bias, int M, int N, int K,
    int lda, int ldb, int ldc, long sA, long sB, long sC, int tri, int kcausal)
{
  A  += (long)blockIdx.z * sA;
  Bt += (long)blockIdx.z * sB;
  C  += (long)blockIdx.z * sC;
  __shared__ alignas(16) char lds[32768];   // 2 slots x (A 8KB + B 8KB)
  int bx = blockIdx.x, by = blockIdx.y;
  if (tri) { int t = blockIdx.x, i = 0; while (t > i) { t -= i + 1; i++; } bx = i; by = t; }
  const int tid = threadIdx.x;
  const int wave = tid >> 6, lane = tid & 63;
  const int lo = lane & 15, hi = lane >> 4;
  const int hi2 = hi ^ ((lo >> 1) & 3);
  const int wr = wave >> 1, wc = wave & 1;
  const int row0 = bx * 128, col0 = by * 128;
  const int srow  = lane >> 2;
  const int skoff = (((lane & 3) ^ ((lane >> 3) & 3)) << 3);
  const int Keff = kcausal ? (K < row0 + 128 ? K : row0 + 128) : K;
  const int NT = Keff >> 5;

  auto stage = [&](int t) {
    char* base = lds + (t & 1) * 16384;
    const int kk = (t << 5) + skoff;
#pragma unroll
    for (int c = 0; c < 2; ++c) {
      const int seg = c*4 + wave;
      int ra = row0 + seg*16 + srow; ra = ra < M ? ra : M-1;
      llds16(A + (long)ra*lda + kk, base + seg*1024);
      int rb = col0 + seg*16 + srow; rb = rb < N ? rb : N-1;
      llds16(Bt + (long)rb*ldb + kk, base + 8192 + seg*1024);
    }
  };

  f32x4 acc[4][4] = {};

  stage(0);
  asm volatile("s_waitcnt vmcnt(0)" ::: "memory");
  __builtin_amdgcn_s_barrier();
  __builtin_amdgcn_sched_barrier(0);

  for (int t = 0; t < NT; t++) {
    const char* As = lds + (t & 1) * 16384;
    const char* Bs = As + 8192;
    if (t + 1 < NT) stage(t + 1);   // lands during this tile's reads + MFMA
    bf16x8 af[4], bfv[4];
#pragma unroll
    for (int m = 0; m < 4; m++)
      af[m] = *(const bf16x8*)(As + ((wr*64 + m*16 + lo) << 6) + (hi2 << 4));
#pragma unroll
    for (int n = 0; n < 4; n++)
      bfv[n] = *(const bf16x8*)(Bs + ((wc*64 + n*16 + lo) << 6) + (hi2 << 4));
    __builtin_amdgcn_s_setprio(1);
#pragma unroll
    for (int m = 0; m < 4; m++)
#pragma unroll
      for (int n = 0; n < 4; n++)
        acc[m][n] = __builtin_amdgcn_mfma_f32_16x16x32_bf16(af[m], bfv[n], acc[m][n], 0, 0, 0);
    __builtin_amdgcn_s_setprio(0);
    __builtin_amdgcn_sched_barrier(0);
    asm volatile("s_waitcnt vmcnt(0)" ::: "memory");
    __builtin_amdgcn_sched_barrier(0);
    __builtin_amdgcn_s_barrier();
    __builtin_amdgcn_sched_barrier(0);
  }

#pragma unroll
  for (int m = 0; m < 4; m++) {
    const int rbase = row0 + wr*64 + m*16 + hi*4;
#pragma unroll
    for (int n = 0; n < 4; n++) {
      const int cc = col0 + wc*64 + n*16 + lo;
      if (cc >= N) continue;
      const float bb = bias ? bias[cc] : 0.0f;
#pragma unroll
      for (int j = 0; j < 4; j++) {
        const int rr = rbase + j;
        if (rr < M) store_out(&C[(long)rr*ldc + cc], acc[m][n][j] + bb);
      }
    }
  }
}

// ---------------- weight prep: W[K,N] f32 -> Wt[N,K] bf16, z-indexed up to 4 pairs ----------------
__global__ __launch_bounds__(256) void wprep4_kernel(
    const float* W0, const float* W1, const float* W2, const float* W3,
    bf16* T0, bf16* T1, bf16* T2, bf16* T3, int K, int N)
{
  const int z = blockIdx.z;
  const float* W = z == 0 ? W0 : z == 1 ? W1 : z == 2 ? W2 : W3;
  bf16* T = z == 0 ? T0 : z == 1 ? T1 : z == 2 ? T2 : T3;
  __shared__ bf16 t[32][33];
  const int k0 = blockIdx.x * 32, n0 = blockIdx.y * 32;
  const int tx = threadIdx.x & 31, ty = threadIdx.x >> 5;
#pragma unroll
  for (int i = 0; i < 4; i++)
    t[ty + i*8][tx] = __float2bfloat16(W[(long)(k0 + ty + i*8)*N + n0 + tx]);
  __syncthreads();
#pragma unroll
  for (int i = 0; i < 4; i++)
    T[(long)(n0 + ty + i*8)*K + k0 + tx] = t[tx][ty + i*8];
}

// ---------------- bf16 transpose with zero-pad: in[R x Cc (ld inLD)] -> out[Cc x outLD] ----------------
__global__ __launch_bounds__(256) void transpose_pad_kernel(
    const bf16* __restrict__ in, bf16* __restrict__ out,
    int R, int Cc, int inLD, int outLD, long inBatch, long outBatch)
{
  in  += (long)blockIdx.z * inBatch;
  out += (long)blockIdx.z * outBatch;
  __shared__ bf16 t[32][33];
  const int r0 = blockIdx.x * 32, c0 = blockIdx.y * 32;
  const int tx = threadIdx.x & 31, ty = threadIdx.x >> 5;
#pragma unroll
  for (int i = 0; i < 4; i++) {
    const int r = r0 + ty + i*8;
    bf16 v = __float2bfloat16(0.0f);
    if (r < R) v = in[(long)r*inLD + c0 + tx];
    t[ty + i*8][tx] = v;
  }
  __syncthreads();
#pragma unroll
  for (int i = 0; i < 4; i++) {
    const int oc = r0 + tx;
    const int orow = c0 + ty + i*8;
    if (oc < outLD) out[(long)orow*outLD + oc] = t[tx][ty + i*8];
  }
}

// ---------------- bias concat (up to 3) ----------------
__global__ __launch_bounds__(256) void concat_bias_kernel(
    const float* a, const float* b, const float* c, int n1, int n2, int n3, float* out)
{
  const int i = blockIdx.x * 256 + threadIdx.x;
  if (i >= n1 + n2 + n3) return;
  out[i] = i < n1 ? a[i] : (i < n1 + n2 ? b[i - n1] : c[i - n1 - n2]);
}

// ---------------- embedding + sinusoidal positional encoding (bf16 out only) ----------------
__global__ __launch_bounds__(256) void embed_kernel(
    const int* __restrict__ tok, const float* __restrict__ tbl,
    bf16* __restrict__ xb)
{
  const int row = blockIdx.x;
  const int s = row & 511;
  const float pos = (float)s;
  const float* te = tbl + (long)tok[row] * 1024;
  const int d0 = threadIdx.x * 4;
  float4 v = *(const float4*)(te + d0);
  float o[4] = {v.x, v.y, v.z, v.w};
#pragma unroll
  for (int k = 0; k < 4; k++) {
    const int d = d0 + k;
    const int i2 = d & ~1;
    const float ang = pos * exp2f((float)i2 * -0.0129762816f);
    o[k] += (d & 1) ? __cosf(ang) : __sinf(ang);
  }
  bf16 ob[4];
#pragma unroll
  for (int k = 0; k < 4; k++) ob[k] = __float2bfloat16(o[k]);
  *(ushort4*)((unsigned short*)xb + (long)row*1024 + d0) = *(ushort4*)ob;
}

// ---------------- f32 -> bf16 copy ----------------
__global__ __launch_bounds__(256) void cvt_bf16_kernel(const float* __restrict__ in, bf16* __restrict__ out, long n)
{
  long i = (long)blockIdx.x * blockDim.x + threadIdx.x;
  if (i < n) out[i] = __float2bfloat16(in[i]);
}

// ---------------- causal softmax over scores [B*S rows][512] ----------------
__global__ __launch_bounds__(64) void softmax_causal_kernel(
    const float* __restrict__ Sc, bf16* __restrict__ P)
{
  const int row = blockIdx.x;
  const int q = row & 511;
  const float* srow = Sc + (long)row * 512;
  bf16* prow = P + (long)row * 512;
  const int lane = threadIdx.x;
  const float scale = 0.03125f;
  float mx = -1e30f;
  for (int j = lane; j <= q; j += 64) mx = fmaxf(mx, srow[j]);
  mx = wredmax(mx);
  float sum = 0.0f;
  for (int j = lane; j <= q; j += 64) sum += expf((srow[j] - mx) * scale);
  sum = wredsum(sum);
  const float inv = 1.0f / sum;
  for (int j = lane; j < 512; j += 64) {
    float p = (j <= q) ? expf((srow[j] - mx) * scale) * inv : 0.0f;
    prow[j] = __float2bfloat16(p);
  }
}

// ---------------- cross softmax: rows of 197 valid (ld 224) ----------------
__global__ __launch_bounds__(64) void softmax_cross_kernel(
    const float* __restrict__ Sc, bf16* __restrict__ P)
{
  const int row = blockIdx.x;
  const float* srow = Sc + (long)row * 224;
  bf16* prow = P + (long)row * 224;
  const int lane = threadIdx.x;
  const float scale = 0.03125f;
  float mx = -1e30f;
  for (int j = lane; j < 197; j += 64) mx = fmaxf(mx, srow[j]);
  mx = wredmax(mx);
  float sum = 0.0f;
  for (int j = lane; j < 197; j += 64) sum += expf((srow[j] - mx) * scale);
  sum = wredsum(sum);
  const float inv = 1.0f / sum;
  for (int j = lane; j < 224; j += 64) {
    float p = (j < 197) ? expf((srow[j] - mx) * scale) * inv : 0.0f;
    prow[j] = __float2bfloat16(p);
  }
}

// ---------------- add residual + LayerNorm (bf16 in, bf16 out) ----------------
__global__ __launch_bounds__(256) void add_ln_kernel(
    const bf16* __restrict__ Acc, const bf16* __restrict__ Res,
    const float* __restrict__ g, const float* __restrict__ b,
    bf16* __restrict__ outb)
{
  const int row = blockIdx.x;
  const unsigned short* a = (const unsigned short*)Acc + (long)row * 1024;
  const unsigned short* r = (const unsigned short*)Res + (long)row * 1024;
  const int d0 = threadIdx.x * 4;
  ushort4 av = *(const ushort4*)(a + d0);
  ushort4 rv = *(const ushort4*)(r + d0);
  float vals[4] = { b2f(av.x) + b2f(rv.x), b2f(av.y) + b2f(rv.y),
                    b2f(av.z) + b2f(rv.z), b2f(av.w) + b2f(rv.w) };
  float s = vals[0] + vals[1] + vals[2] + vals[3];
  float ss = vals[0]*vals[0] + vals[1]*vals[1] + vals[2]*vals[2] + vals[3]*vals[3];
  s = wredsum(s); ss = wredsum(ss);
  __shared__ float sh[8];
  const int wave = threadIdx.x >> 6, lane = threadIdx.x & 63;
  if (lane == 0) { sh[wave] = s; sh[wave+4] = ss; }
  __syncthreads();
  s  = sh[0] + sh[1] + sh[2] + sh[3];
  ss = sh[4] + sh[5] + sh[6] + sh[7];
  const float mean = s * (1.0f/1024.0f);
  const float var  = ss * (1.0f/1024.0f) - mean*mean;
  const float inv  = rsqrtf(var + 1e-5f);
  bf16 ob[4];
#pragma unroll
  for (int i = 0; i < 4; i++) {
    const int d = d0 + i;
    ob[i] = __float2bfloat16((vals[i] - mean) * inv * g[d] + b[d]);
  }
  *(ushort4*)((unsigned short*)outb + (long)row*1024 + d0) = *(ushort4*)ob;
}

// =======================================================================================
extern "C" void kernel_launch(void* const* d_in, const int* in_sizes, int n_in,
                              void* d_out, int out_size, void* d_ws, size_t ws_size,
                              hipStream_t stream) {
  const int*   tokens = (const int*)  d_in[0];
  const float* img    = (const float*)d_in[1];
  const float* emb    = (const float*)d_in[2];
  const float* Wq1    = (const float*)d_in[3];
  const float* bq1    = (const float*)d_in[4];
  const float* Wk1    = (const float*)d_in[5];
  const float* bk1    = (const float*)d_in[6];
  const float* Wv1    = (const float*)d_in[7];
  const float* bv1    = (const float*)d_in[8];
  const float* g1     = (const float*)d_in[9];
  const float* b1     = (const float*)d_in[10];
  const float* Wq2    = (const float*)d_in[11];
  const float* bq2    = (const float*)d_in[12];
  const float* Wk2    = (const float*)d_in[13];
  const float* bk2    = (const float*)d_in[14];
  const float* Wv2    = (const float*)d_in[15];
  const float* bv2    = (const float*)d_in[16];
  const float* g2     = (const float*)d_in[17];
  const float* b2     = (const float*)d_in[18];
  const float* Wp     = (const float*)d_in[19];
  const float* bp     = (const float*)d_in[20];
  float* out = (float*)d_out;

  const int B = 8, S = 512, D = 1024, DI = 768, NI = 197, NIP = 224, V = 32000;
  const int M = B * S;          // 4096
  const int MI = B * NI;        // 1576

  char* ws = (char*)d_ws;
  size_t off = 0;
  auto alloc = [&](size_t bytes) -> char* {
    char* p = ws + off; off += (bytes + 255) & ~(size_t)255; return p;
  };
  // NOTE: Wq1t/Wk1t/Wv1t contiguous -> fused QKV B-matrix; Wk2t/Wv2t contiguous -> KV2.
  bf16* Wq1t = (bf16*)alloc((size_t)D*D*2);
  bf16* Wk1t = (bf16*)alloc((size_t)D*D*2);
  bf16* Wv1t = (bf16*)alloc((size_t)D*D*2);
  bf16* Wq2t = (bf16*)alloc((size_t)D*D*2);
  bf16* Wk2t = (bf16*)alloc((size_t)D*DI*2);
  bf16* Wv2t = (bf16*)alloc((size_t)D*DI*2);
  bf16* Wpt  = (bf16*)alloc((size_t)V*D*2);
  float* bqkv= (float*)alloc((size_t)3*D*4);
  float* bkv2= (float*)alloc((size_t)2*D*4);
  bf16*  xb  = (bf16*) alloc((size_t)M*D*2);
  bf16*  imgb= (bf16*) alloc((size_t)MI*DI*2);
  bf16*  QKV = (bf16*) alloc((size_t)M*3*D*2);   // [M][3072]: Q | K | V
  bf16*  Vt  = (bf16*) alloc((size_t)M*D*2);
  float* sc1 = (float*)alloc((size_t)B*S*S*4);
  bf16*  P1  = (bf16*) alloc((size_t)B*S*S*2);
  bf16*  ao1 = (bf16*) alloc((size_t)M*D*2);
  bf16*  x2b = (bf16*) alloc((size_t)M*D*2);
  bf16*  Q2  = (bf16*) alloc((size_t)M*D*2);
  bf16*  KV2 = (bf16*) alloc((size_t)MI*2*D*2);  // [MI][2048]: K2 | V2
  bf16*  V2t = (bf16*) alloc((size_t)B*D*NIP*2);
  float* sc2 = (float*)alloc((size_t)B*S*NIP*4);
  bf16*  P2  = (bf16*) alloc((size_t)B*S*NIP*2);
  bf16*  ao2 = (bf16*) alloc((size_t)M*D*2);
  bf16*  x3b = (bf16*) alloc((size_t)M*D*2);
  (void)ws_size; (void)in_sizes; (void)n_in; (void)out_size;

  // --- weight prep (f32 [K,N] -> bf16 [N,K]) ---
  wprep4_kernel<<<dim3(D/32,  D/32, 4), 256, 0, stream>>>(Wq1, Wk1, Wv1, Wq2, Wq1t, Wk1t, Wv1t, Wq2t, D, D);
  wprep4_kernel<<<dim3(DI/32, D/32, 2), 256, 0, stream>>>(Wk2, Wv2, nullptr, nullptr, Wk2t, Wv2t, nullptr, nullptr, DI, D);
  wprep4_kernel<<<dim3(D/32,  V/32, 1), 256, 0, stream>>>(Wp, nullptr, nullptr, nullptr, Wpt, nullptr, nullptr, nullptr, D, V);
  concat_bias_kernel<<<(3*D+255)/256, 256, 0, stream>>>(bq1, bk1, bv1, D, D, D, bqkv);
  concat_bias_kernel<<<(2*D+255)/256, 256, 0, stream>>>(bk2, bv2, nullptr, D, D, 0, bkv2);

  // --- embed + img convert ---
  embed_kernel<<<M, 256, 0, stream>>>(tokens, emb, xb);
  {
    long n = (long)MI * DI;
    cvt_bf16_kernel<<<(int)((n + 255)/256), 256, 0, stream>>>(img, imgb, n);
  }

  auto gemmF = [&](const bf16* A, const bf16* Bt, float* C, const float* bias,
                   int m, int n, int k, int lda, int ldb, int ldc,
                   long sA, long sB, long sC, int batch) {
    dim3 g((m+127)/128, (n+127)/128, batch);
    gemm_bt_kernel<float><<<g, 256, 0, stream>>>(A, Bt, C, bias, m, n, k, lda, ldb, ldc, sA, sB, sC, 0, 0);
  };
  auto gemmB = [&](const bf16* A, const bf16* Bt, bf16* C, const float* bias,
                   int m, int n, int k, int lda, int ldb, int ldc,
                   long sA, long sB, long sC, int batch) {
    dim3 g((m+127)/128, (n+127)/128, batch);
    gemm_bt_kernel<bf16><<<g, 256, 0, stream>>>(A, Bt, C, bias, m, n, k, lda, ldb, ldc, sA, sB, sC, 0, 0);
  };

  // --- block 1: causal self-attention (fused QKV GEMM via 256^2 kernel: grid 16x12=192) ---
  gemm256_kernel<bf16><<<dim3((M/256)*(3*D/256)), 512, 0, stream>>>(
      xb, Wq1t, QKV, bqkv, M, 3*D, D, D, D, 3*D);
  transpose_pad_kernel<<<dim3(S/32, D/32, B), 256, 0, stream>>>(
      QKV + 2*D, Vt, S, D, 3*D, S, (long)S*3*D, (long)D*S);
  // sc1: lower-triangle blocks only (10 of 16 per batch)
  gemm_bt_kernel<float><<<dim3(10, 1, B), 256, 0, stream>>>(
      QKV, QKV + D, sc1, nullptr, S, S, D, 3*D, 3*D, S,
      (long)S*3*D, (long)S*3*D, (long)S*S, 1, 0);
  softmax_causal_kernel<<<M, 64, 0, stream>>>(sc1, P1);
  // PV1: K truncated to row0+128 (P is causally zero beyond)
  gemm_bt_kernel<bf16><<<dim3(S/128, D/128, B), 256, 0, stream>>>(
      P1, Vt, ao1, nullptr, S, D, S, S, S, D,
      (long)S*S, (long)D*S, (long)S*D, 0, 1);
  add_ln_kernel<<<M, 256, 0, stream>>>(ao1, xb, g1, b1, x2b);

  // --- block 2: cross-attention over image tokens (Q2 via 256^2; fused K2V2 GEMM N=2048) ---
  gemm256_kernel<bf16><<<dim3((M/256)*(D/256)), 512, 0, stream>>>(
      x2b, Wq2t, Q2, bq2, M, D, D, D, D, D);
  gemmB(imgb, Wk2t, KV2, bkv2, MI, 2*D, DI, DI, DI, 2*D, 0, 0, 0, 1);
  transpose_pad_kernel<<<dim3((NIP+31)/32, D/32, B), 256, 0, stream>>>(
      KV2 + D, V2t, NI, D, 2*D, NIP, (long)NI*2*D, (long)D*NIP);
  gemmF(Q2, KV2, sc2, nullptr, S, NI, D, D, 2*D, NIP, (long)S*D, (long)NI*2*D, (long)S*NIP, B);
  softmax_cross_kernel<<<M, 64, 0, stream>>>(sc2, P2);
  gemmB(P2, V2t, ao2, nullptr, S, D, NIP, NIP, NIP, D, (long)S*NIP, (long)D*NIP, (long)S*D, B);
  add_ln_kernel<<<M, 256, 0, stream>>>(ao2, x2b, g2, b2, x3b);

  // --- vocab projection: R8 ring-4 256^2 kernel (grid 16x125 = 2000 blocks) ---
  gemm256_kernel<float><<<dim3((M/256)*(V/256)), 512, 0, stream>>>(
      x3b, Wpt, out, bp, M, V, D, D, D, V);
}

// Round 12
// 634.536 us; speedup vs baseline: 1.1590x; 1.0335x over previous
//
#include <hip/hip_runtime.h>
#include <hip/hip_bf16.h>

// Decoder forward: embed+posenc -> causal self-attn -> LN -> cross-attn(img) -> LN -> vocab proj
// B=8 S=512 D=1024 DI=768 NI=197(pad 224) V=32000. GEMMs bf16 MFMA (16x16x32), f32 accum.
// R12: gemm256 -> faithful m201 8-phase schedule (BK=64, 2 K-tiles/iter, dual barrier/phase,
//      stage-by-death-order, vmcnt(6) at P4/P8 only). Tail identical to R11.

#define DEV __device__ __forceinline__

typedef __bf16 bf16x8 __attribute__((ext_vector_type(8)));
typedef float f32x4 __attribute__((ext_vector_type(4)));
typedef unsigned int u32;
typedef __hip_bfloat16 bf16;

DEV void llds16(const void* g, void* l) {
  __builtin_amdgcn_global_load_lds((const __attribute__((address_space(1))) u32*)g,
                                   (__attribute__((address_space(3))) u32*)l, 16, 0, 0);
}

DEV float wredsum(float v){
#pragma unroll
  for (int o = 32; o; o >>= 1) v += __shfl_xor(v, o, 64);
  return v;
}
DEV float wredmax(float v){
#pragma unroll
  for (int o = 32; o; o >>= 1) v = fmaxf(v, __shfl_xor(v, o, 64));
  return v;
}

DEV float b2f(unsigned short x){ return __uint_as_float((u32)x << 16); }

DEV void store_out(float* p, float v){ *p = v; }
DEV void store_out(bf16* p, float v){ *p = __float2bfloat16(v); }

// ================= big GEMM: C[M,N] = A[M,K] @ Bt[N,K]^T + bias =================
// m201-style 8-phase: 256x256 tile, BK=64, 8 waves (2Mx4N), per-wave 128x64 out.
// LDS 128KiB = 2 slots x 64KB (A[256][64] + B[256][64] bf16, 128B rows).
// Per iter: process K-tiles (2i slot0: P1-P4, 2i+1 slot1: P5-P8); each phase:
//   {ds_read quadrant frags} {stage 1 half-tile = 2 gloads} BAR lgkm(0) {16 MFMA} [vmcnt] BAR
// Stage schedule (unit -> phase, by read-death): P1:AL(2i+1) P2:AE(2i+2) P3:BE(2i+2)
//   P4:BL(2i+2) P5:AL(2i+2) P6:AE(2i+3) P7:BE(2i+3) P8:BL(2i+3).
// vmcnt(6) at P4/P8 = 3 half-tiles (6 loads) stay in flight; ledger drains exactly the
// tile read by the following 4 phases. Swizzle: phys 16B slot = (ks*4+hi)^(row&7),
// pre-swizzled global koff = ((lane&7)^(lane>>3))*8. Requires M%256==N%256==0, K%128==0.
#define SBAR __builtin_amdgcn_sched_barrier(0)
#define HBAR __builtin_amdgcn_s_barrier()
#define LGKM0 asm volatile("s_waitcnt lgkmcnt(0)" ::: "memory")
#define VMC6 asm volatile("s_waitcnt vmcnt(6)" ::: "memory")
#define VMC0 asm volatile("s_waitcnt vmcnt(0)" ::: "memory")

// read A quadrant mh (4 m-frags x 2 ks) from slot
#define RD_A(slot, mh) do { \
  _Pragma("unroll") for (int m = 0; m < 4; m++) { \
    const int r_ = wr*128 + ((mh)*4 + m)*16 + lo; \
    _Pragma("unroll") for (int ks = 0; ks < 2; ks++) \
      af[m*2+ks] = *(const bf16x8*)((slot) + r_*128 + ((((ks<<2)|hi) ^ x7) << 4)); \
  } } while(0)
// read B quadrant nh (2 n-frags x 2 ks) from slot
#define RD_B(slot, nh) do { \
  _Pragma("unroll") for (int n = 0; n < 2; n++) { \
    const int gn_ = (nh)*2 + n; \
    const int r_ = wc*64 + gn_*16 + lo; \
    _Pragma("unroll") for (int ks = 0; ks < 2; ks++) \
      bfv[gn_*2+ks] = *(const bf16x8*)((slot) + 32768 + r_*128 + ((((ks<<2)|hi) ^ x7) << 4)); \
  } } while(0)
// MFMA one C-quadrant (mh, nh): 16 MFMAs
#define MQ(mh, nh) do { \
  __builtin_amdgcn_s_setprio(1); \
  _Pragma("unroll") for (int ks = 0; ks < 2; ks++) \
  _Pragma("unroll") for (int m = 0; m < 4; m++) \
  _Pragma("unroll") for (int n = 0; n < 2; n++) \
    acc[(mh)*4+m][(nh)*2+n] = __builtin_amdgcn_mfma_f32_16x16x32_bf16( \
        af[m*2+ks], bfv[((nh)*2+n)*2+ks], acc[(mh)*4+m][(nh)*2+n], 0, 0, 0); \
  __builtin_amdgcn_s_setprio(0); \
  } while(0)

template<typename OutT>
__global__ __launch_bounds__(512, 1) void gemm256_kernel(
    const bf16* __restrict__ A, const bf16* __restrict__ Bt, OutT* __restrict__ C,
    const float* __restrict__ bias, int M, int N, int K, int lda, int ldb, int ldc)
{
  __shared__ alignas(16) char lds[131072];
  const int tid = threadIdx.x;
  const int wave = tid >> 6, lane = tid & 63;
  const int lo = lane & 15, hi = lane >> 4;
  const int x7 = lo & 7;
  const int wr = wave >> 2, wc = wave & 3;
  const int lr8 = lane >> 3;
  const int koff = ((lane & 7) ^ lr8) << 3;   // pre-swizzled global k offset (elements)

  const int nbx = M >> 8;
  const int nwg = nbx * (N >> 8);
  int id = blockIdx.x;
  int g = (nwg & 7) ? id : ((id & 7) * (nwg >> 3) + (id >> 3));
  const int row0 = (g % nbx) * 256, col0 = (g / nbx) * 256;
  const int NT2 = K >> 6;   // K-tiles of 64

  // stage one half-tile (2 gloads/thread). kind: 0=A-early 1=B-early 2=B-late 3=A-late.
  // A-early rows {0-63,128-191}; A-late {64-127,192-255};
  // B-early rows {0-31,64-95,128-159,192-223}; B-late = +32.
  auto stage = [&](int kind, int t) {
    if (t >= NT2) return;
    char* slot = lds + (t & 1) * 65536;
    const int kk = (t << 6) + koff;
#pragma unroll
    for (int j = 0; j < 2; j++) {
      if (kind == 0 || kind == 3) {
        const int br = ((kind == 3) ? 64 : 0) + j*128 + wave*8;
        llds16(A + (long)(row0 + br + lr8)*lda + kk, slot + br*128);
      } else {
        const int br = ((kind == 2) ? 32 : 0) + (wave&3)*8 + (wave>>2)*64 + j*128;
        llds16(Bt + (long)(col0 + br + lr8)*ldb + kk, slot + 32768 + br*128);
      }
    }
  };

  f32x4 acc[8][4] = {};
  bf16x8 af[8], bfv[8];

  // prologue: tile0 all 4 units + tile1 first 3; drain tile0 (8 loads) exactly.
  stage(0,0); stage(1,0); stage(2,0); stage(3,0);
  stage(0,1); stage(1,1); stage(2,1);
  VMC6;
  HBAR; SBAR;

  for (int it = 0; it < (NT2 >> 1); it++) {
    const int ta = it*2, tb = ta+1;
    const char* sa = lds;            // even tile -> slot0
    const char* sb = lds + 65536;    // odd tile -> slot1
    // ---- P1 ----
    RD_A(sa, 0); RD_B(sa, 0); SBAR; stage(3, tb); SBAR;
    HBAR; LGKM0; SBAR; MQ(0, 0); SBAR; HBAR; SBAR;
    // ---- P2 ----
    RD_B(sa, 1); SBAR; stage(0, ta+2); SBAR;
    HBAR; LGKM0; SBAR; MQ(0, 1); SBAR; HBAR; SBAR;
    // ---- P3 ----
    RD_A(sa, 1); SBAR; stage(1, ta+2); SBAR;
    HBAR; LGKM0; SBAR; MQ(1, 0); SBAR; HBAR; SBAR;
    // ---- P4 ----
    stage(2, ta+2); SBAR;
    HBAR; SBAR; MQ(1, 1); SBAR;
    if (ta+2 < NT2) { VMC6; } else { VMC0; }
    HBAR; SBAR;
    // ---- P5 ----
    RD_A(sb, 0); RD_B(sb, 0); SBAR; stage(3, ta+2); SBAR;
    HBAR; LGKM0; SBAR; MQ(0, 0); SBAR; HBAR; SBAR;
    // ---- P6 ----
    RD_B(sb, 1); SBAR; stage(0, tb+2); SBAR;
    HBAR; LGKM0; SBAR; MQ(0, 1); SBAR; HBAR; SBAR;
    // ---- P7 ----
    RD_A(sb, 1); SBAR; stage(1, tb+2); SBAR;
    HBAR; LGKM0; SBAR; MQ(1, 0); SBAR; HBAR; SBAR;
    // ---- P8 ----
    stage(2, tb+2); SBAR;
    HBAR; SBAR; MQ(1, 1); SBAR;
    if (tb+2 < NT2) { VMC6; } else { VMC0; }
    HBAR; SBAR;
  }

#pragma unroll
  for (int m = 0; m < 8; m++) {
    const int r = row0 + wr * 128 + m * 16 + hi * 4;
#pragma unroll
    for (int n = 0; n < 4; n++) {
      const int c = col0 + wc * 64 + n * 16 + lo;
      const float bb = bias ? bias[c] : 0.0f;
#pragma unroll
      for (int j = 0; j < 4; j++)
        store_out(&C[(long)(r + j) * ldc + c], acc[m][n][j] + bb);
    }
  }
}

// ---------------- small GEMM: C[M,N] = A[M,K] @ Bt[N,K]^T (+bias[N]) ----------------
// 128x128 tile, BK=32, 4 waves, ring-2 double-buffered (32KB LDS), 1 barrier/K-step.
// tri: lower-triangle block grid. kcausal: Keff = min(K, row0+128).
template<typename OutT>
__global__ __launch_bounds__(256) void gemm_bt_kernel(
    const bf16* __restrict__ A, const bf16* __restrict__ Bt, OutT* __restrict__ C,
    const float* __restrict__ bias, int M, int N, int K,
    int lda, int ldb, int ldc, long sA, long sB, long sC, int tri, int kcausal)
{
  A  += (long)blockIdx.z * sA;
  Bt += (long)blockIdx.z * sB;
  C  += (long)blockIdx.z * sC;
  __shared__ alignas(16) char lds[32768];
  int bx = blockIdx.x, by = blockIdx.y;
  if (tri) { int t = blockIdx.x, i = 0; while (t > i) { t -= i + 1; i++; } bx = i; by = t; }
  const int tid = threadIdx.x;
  const int wave = tid >> 6, lane = tid & 63;
  const int lo = lane & 15, hi = lane >> 4;
  const int hi2 = hi ^ ((lo >> 1) & 3);
  const int wr = wave >> 1, wc = wave & 1;
  const int row0 = bx * 128, col0 = by * 128;
  const int srow  = lane >> 2;
  const int skoff = (((lane & 3) ^ ((lane >> 3) & 3)) << 3);
  const int Keff = kcausal ? (K < row0 + 128 ? K : row0 + 128) : K;
  const int NT = Keff >> 5;

  auto stage = [&](int t) {
    char* base = lds + (t & 1) * 16384;
    const int kk = (t << 5) + skoff;
#pragma unroll
    for (int c = 0; c < 2; ++c) {
      const int seg = c*4 + wave;
      int ra = row0 + seg*16 + srow; ra = ra < M ? ra : M-1;
      llds16(A + (long)ra*lda + kk, base + seg*1024);
      int rb = col0 + seg*16 + srow; rb = rb < N ? rb : N-1;
      llds16(Bt + (long)rb*ldb + kk, base + 8192 + seg*1024);
    }
  };

  f32x4 acc[4][4] = {};

  stage(0);
  VMC0;
  HBAR; SBAR;

  for (int t = 0; t < NT; t++) {
    const char* As = lds + (t & 1) * 16384;
    const char* Bs = As + 8192;
    if (t + 1 < NT) stage(t + 1);
    bf16x8 af[4], bfv[4];
#pragma unroll
    for (int m = 0; m < 4; m++)
      af[m] = *(const bf16x8*)(As + ((wr*64 + m*16 + lo) << 6) + (hi2 << 4));
#pragma unroll
    for (int n = 0; n < 4; n++)
      bfv[n] = *(const bf16x8*)(Bs + ((wc*64 + n*16 + lo) << 6) + (hi2 << 4));
    __builtin_amdgcn_s_setprio(1);
#pragma unroll
    for (int m = 0; m < 4; m++)
#pragma unroll
      for (int n = 0; n < 4; n++)
        acc[m][n] = __builtin_amdgcn_mfma_f32_16x16x32_bf16(af[m], bfv[n], acc[m][n], 0, 0, 0);
    __builtin_amdgcn_s_setprio(0);
    SBAR;
    VMC0;
    SBAR;
    HBAR; SBAR;
  }

#pragma unroll
  for (int m = 0; m < 4; m++) {
    const int rbase = row0 + wr*64 + m*16 + hi*4;
#pragma unroll
    for (int n = 0; n < 4; n++) {
      const int cc = col0 + wc*64 + n*16 + lo;
      if (cc >= N) continue;
      const float bb = bias ? bias[cc] : 0.0f;
#pragma unroll
      for (int j = 0; j < 4; j++) {
        const int rr = rbase + j;
        if (rr < M) store_out(&C[(long)rr*ldc + cc], acc[m][n][j] + bb);
      }
    }
  }
}

// ---------------- weight prep: W[K,N] f32 -> Wt[N,K] bf16, z-indexed up to 4 pairs ----------------
__global__ __launch_bounds__(256) void wprep4_kernel(
    const float* W0, const float* W1, const float* W2, const float* W3,
    bf16* T0, bf16* T1, bf16* T2, bf16* T3, int K, int N)
{
  const int z = blockIdx.z;
  const float* W = z == 0 ? W0 : z == 1 ? W1 : z == 2 ? W2 : W3;
  bf16* T = z == 0 ? T0 : z == 1 ? T1 : z == 2 ? T2 : T3;
  __shared__ bf16 t[32][33];
  const int k0 = blockIdx.x * 32, n0 = blockIdx.y * 32;
  const int tx = threadIdx.x & 31, ty = threadIdx.x >> 5;
#pragma unroll
  for (int i = 0; i < 4; i++)
    t[ty + i*8][tx] = __float2bfloat16(W[(long)(k0 + ty + i*8)*N + n0 + tx]);
  __syncthreads();
#pragma unroll
  for (int i = 0; i < 4; i++)
    T[(long)(n0 + ty + i*8)*K + k0 + tx] = t[tx][ty + i*8];
}

// ---------------- bf16 transpose with zero-pad: in[R x Cc (ld inLD)] -> out[Cc x outLD] ----------------
__global__ __launch_bounds__(256) void transpose_pad_kernel(
    const bf16* __restrict__ in, bf16* __restrict__ out,
    int R, int Cc, int inLD, int outLD, long inBatch, long outBatch)
{
  in  += (long)blockIdx.z * inBatch;
  out += (long)blockIdx.z * outBatch;
  __shared__ bf16 t[32][33];
  const int r0 = blockIdx.x * 32, c0 = blockIdx.y * 32;
  const int tx = threadIdx.x & 31, ty = threadIdx.x >> 5;
#pragma unroll
  for (int i = 0; i < 4; i++) {
    const int r = r0 + ty + i*8;
    bf16 v = __float2bfloat16(0.0f);
    if (r < R) v = in[(long)r*inLD + c0 + tx];
    t[ty + i*8][tx] = v;
  }
  __syncthreads();
#pragma unroll
  for (int i = 0; i < 4; i++) {
    const int oc = r0 + tx;
    const int orow = c0 + ty + i*8;
    if (oc < outLD) out[(long)orow*outLD + oc] = t[tx][ty + i*8];
  }
}

// ---------------- bias concat (up to 3) ----------------
__global__ __launch_bounds__(256) void concat_bias_kernel(
    const float* a, const float* b, const float* c, int n1, int n2, int n3, float* out)
{
  const int i = blockIdx.x * 256 + threadIdx.x;
  if (i >= n1 + n2 + n3) return;
  out[i] = i < n1 ? a[i] : (i < n1 + n2 ? b[i - n1] : c[i - n1 - n2]);
}

// ---------------- embedding + sinusoidal positional encoding (bf16 out only) ----------------
__global__ __launch_bounds__(256) void embed_kernel(
    const int* __restrict__ tok, const float* __restrict__ tbl,
    bf16* __restrict__ xb)
{
  const int row = blockIdx.x;
  const int s = row & 511;
  const float pos = (float)s;
  const float* te = tbl + (long)tok[row] * 1024;
  const int d0 = threadIdx.x * 4;
  float4 v = *(const float4*)(te + d0);
  float o[4] = {v.x, v.y, v.z, v.w};
#pragma unroll
  for (int k = 0; k < 4; k++) {
    const int d = d0 + k;
    const int i2 = d & ~1;
    const float ang = pos * exp2f((float)i2 * -0.0129762816f);
    o[k] += (d & 1) ? __cosf(ang) : __sinf(ang);
  }
  bf16 ob[4];
#pragma unroll
  for (int k = 0; k < 4; k++) ob[k] = __float2bfloat16(o[k]);
  *(ushort4*)((unsigned short*)xb + (long)row*1024 + d0) = *(ushort4*)ob;
}

// ---------------- f32 -> bf16 copy ----------------
__global__ __launch_bounds__(256) void cvt_bf16_kernel(const float* __restrict__ in, bf16* __restrict__ out, long n)
{
  long i = (long)blockIdx.x * blockDim.x + threadIdx.x;
  if (i < n) out[i] = __float2bfloat16(in[i]);
}

// ---------------- causal softmax over scores [B*S rows][512] ----------------
__global__ __launch_bounds__(64) void softmax_causal_kernel(
    const float* __restrict__ Sc, bf16* __restrict__ P)
{
  const int row = blockIdx.x;
  const int q = row & 511;
  const float* srow = Sc + (long)row * 512;
  bf16* prow = P + (long)row * 512;
  const int lane = threadIdx.x;
  const float scale = 0.03125f;
  float mx = -1e30f;
  for (int j = lane; j <= q; j += 64) mx = fmaxf(mx, srow[j]);
  mx = wredmax(mx);
  float sum = 0.0f;
  for (int j = lane; j <= q; j += 64) sum += expf((srow[j] - mx) * scale);
  sum = wredsum(sum);
  const float inv = 1.0f / sum;
  for (int j = lane; j < 512; j += 64) {
    float p = (j <= q) ? expf((srow[j] - mx) * scale) * inv : 0.0f;
    prow[j] = __float2bfloat16(p);
  }
}

// ---------------- cross softmax: rows of 197 valid (ld 224) ----------------
__global__ __launch_bounds__(64) void softmax_cross_kernel(
    const float* __restrict__ Sc, bf16* __restrict__ P)
{
  const int row = blockIdx.x;
  const float* srow = Sc + (long)row * 224;
  bf16* prow = P + (long)row * 224;
  const int lane = threadIdx.x;
  const float scale = 0.03125f;
  float mx = -1e30f;
  for (int j = lane; j < 197; j += 64) mx = fmaxf(mx, srow[j]);
  mx = wredmax(mx);
  float sum = 0.0f;
  for (int j = lane; j < 197; j += 64) sum += expf((srow[j] - mx) * scale);
  sum = wredsum(sum);
  const float inv = 1.0f / sum;
  for (int j = lane; j < 224; j += 64) {
    float p = (j < 197) ? expf((srow[j] - mx) * scale) * inv : 0.0f;
    prow[j] = __float2bfloat16(p);
  }
}

// ---------------- add residual + LayerNorm (bf16 in, bf16 out) ----------------
__global__ __launch_bounds__(256) void add_ln_kernel(
    const bf16* __restrict__ Acc, const bf16* __restrict__ Res,
    const float* __restrict__ g, const float* __restrict__ b,
    bf16* __restrict__ outb)
{
  const int row = blockIdx.x;
  const unsigned short* a = (const unsigned short*)Acc + (long)row * 1024;
  const unsigned short* r = (const unsigned short*)Res + (long)row * 1024;
  const int d0 = threadIdx.x * 4;
  ushort4 av = *(const ushort4*)(a + d0);
  ushort4 rv = *(const ushort4*)(r + d0);
  float vals[4] = { b2f(av.x) + b2f(rv.x), b2f(av.y) + b2f(rv.y),
                    b2f(av.z) + b2f(rv.z), b2f(av.w) + b2f(rv.w) };
  float s = vals[0] + vals[1] + vals[2] + vals[3];
  float ss = vals[0]*vals[0] + vals[1]*vals[1] + vals[2]*vals[2] + vals[3]*vals[3];
  s = wredsum(s); ss = wredsum(ss);
  __shared__ float sh[8];
  const int wave = threadIdx.x >> 6, lane = threadIdx.x & 63;
  if (lane == 0) { sh[wave] = s; sh[wave+4] = ss; }
  __syncthreads();
  s  = sh[0] + sh[1] + sh[2] + sh[3];
  ss = sh[4] + sh[5] + sh[6] + sh[7];
  const float mean = s * (1.0f/1024.0f);
  const float var  = ss * (1.0f/1024.0f) - mean*mean;
  const float inv  = rsqrtf(var + 1e-5f);
  bf16 ob[4];
#pragma unroll
  for (int i = 0; i < 4; i++) {
    const int d = d0 + i;
    ob[i] = __float2bfloat16((vals[i] - mean) * inv * g[d] + b[d]);
  }
  *(ushort4*)((unsigned short*)outb + (long)row*1024 + d0) = *(ushort4*)ob;
}

// =======================================================================================
extern "C" void kernel_launch(void* const* d_in, const int* in_sizes, int n_in,
                              void* d_out, int out_size, void* d_ws, size_t ws_size,
                              hipStream_t stream) {
  const int*   tokens = (const int*)  d_in[0];
  const float* img    = (const float*)d_in[1];
  const float* emb    = (const float*)d_in[2];
  const float* Wq1    = (const float*)d_in[3];
  const float* bq1    = (const float*)d_in[4];
  const float* Wk1    = (const float*)d_in[5];
  const float* bk1    = (const float*)d_in[6];
  const float* Wv1    = (const float*)d_in[7];
  const float* bv1    = (const float*)d_in[8];
  const float* g1     = (const float*)d_in[9];
  const float* b1     = (const float*)d_in[10];
  const float* Wq2    = (const float*)d_in[11];
  const float* bq2    = (const float*)d_in[12];
  const float* Wk2    = (const float*)d_in[13];
  const float* bk2    = (const float*)d_in[14];
  const float* Wv2    = (const float*)d_in[15];
  const float* bv2    = (const float*)d_in[16];
  const float* g2     = (const float*)d_in[17];
  const float* b2     = (const float*)d_in[18];
  const float* Wp     = (const float*)d_in[19];
  const float* bp     = (const float*)d_in[20];
  float* out = (float*)d_out;

  const int B = 8, S = 512, D = 1024, DI = 768, NI = 197, NIP = 224, V = 32000;
  const int M = B * S;          // 4096
  const int MI = B * NI;        // 1576

  char* ws = (char*)d_ws;
  size_t off = 0;
  auto alloc = [&](size_t bytes) -> char* {
    char* p = ws + off; off += (bytes + 255) & ~(size_t)255; return p;
  };
  bf16* Wq1t = (bf16*)alloc((size_t)D*D*2);
  bf16* Wk1t = (bf16*)alloc((size_t)D*D*2);
  bf16* Wv1t = (bf16*)alloc((size_t)D*D*2);
  bf16* Wq2t = (bf16*)alloc((size_t)D*D*2);
  bf16* Wk2t = (bf16*)alloc((size_t)D*DI*2);
  bf16* Wv2t = (bf16*)alloc((size_t)D*DI*2);
  bf16* Wpt  = (bf16*)alloc((size_t)V*D*2);
  float* bqkv= (float*)alloc((size_t)3*D*4);
  float* bkv2= (float*)alloc((size_t)2*D*4);
  bf16*  xb  = (bf16*) alloc((size_t)M*D*2);
  bf16*  imgb= (bf16*) alloc((size_t)MI*DI*2);
  bf16*  QKV = (bf16*) alloc((size_t)M*3*D*2);   // [M][3072]: Q | K | V
  bf16*  Vt  = (bf16*) alloc((size_t)M*D*2);
  float* sc1 = (float*)alloc((size_t)B*S*S*4);
  bf16*  P1  = (bf16*) alloc((size_t)B*S*S*2);
  bf16*  ao1 = (bf16*) alloc((size_t)M*D*2);
  bf16*  x2b = (bf16*) alloc((size_t)M*D*2);
  bf16*  Q2  = (bf16*) alloc((size_t)M*D*2);
  bf16*  KV2 = (bf16*) alloc((size_t)MI*2*D*2);  // [MI][2048]: K2 | V2
  bf16*  V2t = (bf16*) alloc((size_t)B*D*NIP*2);
  float* sc2 = (float*)alloc((size_t)B*S*NIP*4);
  bf16*  P2  = (bf16*) alloc((size_t)B*S*NIP*2);
  bf16*  ao2 = (bf16*) alloc((size_t)M*D*2);
  bf16*  x3b = (bf16*) alloc((size_t)M*D*2);
  (void)ws_size; (void)in_sizes; (void)n_in; (void)out_size;

  // --- weight prep (f32 [K,N] -> bf16 [N,K]) ---
  wprep4_kernel<<<dim3(D/32,  D/32, 4), 256, 0, stream>>>(Wq1, Wk1, Wv1, Wq2, Wq1t, Wk1t, Wv1t, Wq2t, D, D);
  wprep4_kernel<<<dim3(DI/32, D/32, 2), 256, 0, stream>>>(Wk2, Wv2, nullptr, nullptr, Wk2t, Wv2t, nullptr, nullptr, DI, D);
  wprep4_kernel<<<dim3(D/32,  V/32, 1), 256, 0, stream>>>(Wp, nullptr, nullptr, nullptr, Wpt, nullptr, nullptr, nullptr, D, V);
  concat_bias_kernel<<<(3*D+255)/256, 256, 0, stream>>>(bq1, bk1, bv1, D, D, D, bqkv);
  concat_bias_kernel<<<(2*D+255)/256, 256, 0, stream>>>(bk2, bv2, nullptr, D, D, 0, bkv2);

  // --- embed + img convert ---
  embed_kernel<<<M, 256, 0, stream>>>(tokens, emb, xb);
  {
    long n = (long)MI * DI;
    cvt_bf16_kernel<<<(int)((n + 255)/256), 256, 0, stream>>>(img, imgb, n);
  }

  auto gemmF = [&](const bf16* A, const bf16* Bt, float* C, const float* bias,
                   int m, int n, int k, int lda, int ldb, int ldc,
                   long sA, long sB, long sC, int batch) {
    dim3 g((m+127)/128, (n+127)/128, batch);
    gemm_bt_kernel<float><<<g, 256, 0, stream>>>(A, Bt, C, bias, m, n, k, lda, ldb, ldc, sA, sB, sC, 0, 0);
  };
  auto gemmB = [&](const bf16* A, const bf16* Bt, bf16* C, const float* bias,
                   int m, int n, int k, int lda, int ldb, int ldc,
                   long sA, long sB, long sC, int batch) {
    dim3 g((m+127)/128, (n+127)/128, batch);
    gemm_bt_kernel<bf16><<<g, 256, 0, stream>>>(A, Bt, C, bias, m, n, k, lda, ldb, ldc, sA, sB, sC, 0, 0);
  };

  // --- block 1: causal self-attention (fused QKV GEMM via 256^2 kernel: grid 192) ---
  gemm256_kernel<bf16><<<dim3((M/256)*(3*D/256)), 512, 0, stream>>>(
      xb, Wq1t, QKV, bqkv, M, 3*D, D, D, D, 3*D);
  transpose_pad_kernel<<<dim3(S/32, D/32, B), 256, 0, stream>>>(
      QKV + 2*D, Vt, S, D, 3*D, S, (long)S*3*D, (long)D*S);
  // sc1: lower-triangle blocks only (10 of 16 per batch)
  gemm_bt_kernel<float><<<dim3(10, 1, B), 256, 0, stream>>>(
      QKV, QKV + D, sc1, nullptr, S, S, D, 3*D, 3*D, S,
      (long)S*3*D, (long)S*3*D, (long)S*S, 1, 0);
  softmax_causal_kernel<<<M, 64, 0, stream>>>(sc1, P1);
  // PV1: K truncated to row0+128 (P causally zero beyond)
  gemm_bt_kernel<bf16><<<dim3(S/128, D/128, B), 256, 0, stream>>>(
      P1, Vt, ao1, nullptr, S, D, S, S, S, D,
      (long)S*S, (long)D*S, (long)S*D, 0, 1);
  add_ln_kernel<<<M, 256, 0, stream>>>(ao1, xb, g1, b1, x2b);

  // --- block 2: cross-attention over image tokens ---
  gemm256_kernel<bf16><<<dim3((M/256)*(D/256)), 512, 0, stream>>>(
      x2b, Wq2t, Q2, bq2, M, D, D, D, D, D);
  gemmB(imgb, Wk2t, KV2, bkv2, MI, 2*D, DI, DI, DI, 2*D, 0, 0, 0, 1);
  transpose_pad_kernel<<<dim3((NIP+31)/32, D/32, B), 256, 0, stream>>>(
      KV2 + D, V2t, NI, D, 2*D, NIP, (long)NI*2*D, (long)D*NIP);
  gemmF(Q2, KV2, sc2, nullptr, S, NI, D, D, 2*D, NIP, (long)S*D, (long)NI*2*D, (long)S*NIP, B);
  softmax_cross_kernel<<<M, 64, 0, stream>>>(sc2, P2);
  gemmB(P2, V2t, ao2, nullptr, S, D, NIP, NIP, NIP, D, (long)S*NIP, (long)D*NIP, (long)S*D, B);
  add_ln_kernel<<<M, 256, 0, stream>>>(ao2, x2b, g2, b2, x3b);

  // --- vocab projection: 8-phase 256^2 kernel (grid 16x125 = 2000 blocks) ---
  gemm256_kernel<float><<<dim3((M/256)*(V/256)), 512, 0, stream>>>(
      x3b, Wpt, out, bp, M, V, D, D, D, V);
}